// Round 1
// baseline (1491.914 us; speedup 1.0000x reference)
//
#include <hip/hip_runtime.h>
#include <math.h>

// LinearAttention: b=32, c=128, h=w=128 (n=16384), heads=4, dim_head=32.
// All fp32 (threshold 1.17e-5 forbids bf16 MFMA; CDNA4 has no fp32 MFMA -> vector FMA).
//
// K1:  per (b, chunk): 4 tiles x 64 positions. x tile -> LDS; k,v GEMM passes;
//      partial S[h][d][e] = sum_p exp(k[d,p]) * v[e,p], Z[h][d] = sum_p exp(k[d,p]).
// K1b: ctx[b][h][d][e] = (sum_ch S) / ((sum_ch Z) * n)       [folds v/n]
// K2:  recompute q tile, per-position softmax over d (*scale), out = ctx^T q_s,
//      y = Wout*out + bout, LayerNorm(channel) * g, write.

#define TP 64
#define NCHUNK 64   // k1 chunks per batch (each does 4 tiles of TP)

__global__ __launch_bounds__(256, 1)
void la_k1(const float* __restrict__ x, const float* __restrict__ Wqkv,
           float* __restrict__ Spart, float* __restrict__ Zpart)
{
    __shared__ float xs[128 * 68];   // x tile [c][p], stride 68 (float4-aligned, 2-way banks)
    __shared__ float ek[128 * 65];   // exp(k) [row][p], stride 65 (conflict-free S reads)
    __shared__ float vT[64 * 132];   // v transposed [p][e], stride 132 (float4-aligned)

    const int tid = threadIdx.x;
    const int b     = blockIdx.y;
    const int chunk = blockIdx.x;
    const int og = tid >> 4;          // 0..15: 8 output rows each
    const int pg = tid & 15;          // 0..15: 4 positions each
    const int hh = tid >> 6;          // head 0..3 (one head per wave)
    const int dr = (tid >> 3) & 7;    // d block 0..7 (4 d each)
    const int er = tid & 7;           // e block 0..7 (4 e each)

    float Sacc[4][4];
    float Zacc[4];
#pragma unroll
    for (int a = 0; a < 4; ++a) {
        Zacc[a] = 0.f;
#pragma unroll
        for (int e = 0; e < 4; ++e) Sacc[a][e] = 0.f;
    }

    for (int t = 0; t < 4; ++t) {
        const int p0 = (chunk * 4 + t) * TP;
        const float* xb = x + (size_t)b * 128 * 16384 + p0;
        // ---- load x tile (coalesced float4) ----
#pragma unroll
        for (int i = 0; i < 8; ++i) {
            const int idx = tid + 256 * i;
            const int c  = idx >> 4;
            const int p4 = (idx & 15) << 2;
            const float4 v = *(const float4*)(xb + (size_t)c * 16384 + p4);
            *(float4*)(&xs[c * 68 + p4]) = v;
        }
        __syncthreads();

        // ---- pass K: rows 128..255 of Wqkv ----
        {
            float acc[8][4];
#pragma unroll
            for (int j = 0; j < 8; ++j)
#pragma unroll
                for (int i = 0; i < 4; ++i) acc[j][i] = 0.f;
#pragma unroll 4
            for (int c = 0; c < 128; c += 4) {
                float4 w[8];
#pragma unroll
                for (int j = 0; j < 8; ++j)
                    w[j] = *(const float4*)(Wqkv + (128 + og * 8 + j) * 128 + c);
                float xv[4][4];
#pragma unroll
                for (int i = 0; i < 4; ++i)
#pragma unroll
                    for (int cc = 0; cc < 4; ++cc)
                        xv[i][cc] = xs[(c + cc) * 68 + pg * 4 + i];
#pragma unroll
                for (int j = 0; j < 8; ++j)
#pragma unroll
                    for (int i = 0; i < 4; ++i)
                        acc[j][i] += w[j].x * xv[i][0] + w[j].y * xv[i][1]
                                   + w[j].z * xv[i][2] + w[j].w * xv[i][3];
            }
#pragma unroll
            for (int j = 0; j < 8; ++j)
#pragma unroll
                for (int i = 0; i < 4; ++i)
                    ek[(og * 8 + j) * 65 + pg * 4 + i] = expf(acc[j][i]);
        }

        // ---- pass V: rows 256..383 of Wqkv, store transposed ----
        {
            float acc[8][4];
#pragma unroll
            for (int j = 0; j < 8; ++j)
#pragma unroll
                for (int i = 0; i < 4; ++i) acc[j][i] = 0.f;
#pragma unroll 4
            for (int c = 0; c < 128; c += 4) {
                float4 w[8];
#pragma unroll
                for (int j = 0; j < 8; ++j)
                    w[j] = *(const float4*)(Wqkv + (256 + og * 8 + j) * 128 + c);
                float xv[4][4];
#pragma unroll
                for (int i = 0; i < 4; ++i)
#pragma unroll
                    for (int cc = 0; cc < 4; ++cc)
                        xv[i][cc] = xs[(c + cc) * 68 + pg * 4 + i];
#pragma unroll
                for (int j = 0; j < 8; ++j)
#pragma unroll
                    for (int i = 0; i < 4; ++i)
                        acc[j][i] += w[j].x * xv[i][0] + w[j].y * xv[i][1]
                                   + w[j].z * xv[i][2] + w[j].w * xv[i][3];
            }
#pragma unroll
            for (int j = 0; j < 8; ++j)
#pragma unroll
                for (int i = 0; i < 4; ++i)
                    vT[(pg * 4 + i) * 132 + og * 8 + j] = acc[j][i];
        }
        __syncthreads();

        // ---- S/Z partial accumulation (per-wave head) ----
#pragma unroll 2
        for (int p = 0; p < TP; ++p) {
            float ekv[4];
#pragma unroll
            for (int a = 0; a < 4; ++a)
                ekv[a] = ek[(hh * 32 + dr * 4 + a) * 65 + p];
            const float4 vv = *(const float4*)(&vT[p * 132 + hh * 32 + er * 4]);
#pragma unroll
            for (int a = 0; a < 4; ++a) {
                Sacc[a][0] += ekv[a] * vv.x;
                Sacc[a][1] += ekv[a] * vv.y;
                Sacc[a][2] += ekv[a] * vv.z;
                Sacc[a][3] += ekv[a] * vv.w;
            }
            if (er == 0) {
#pragma unroll
                for (int a = 0; a < 4; ++a) Zacc[a] += ekv[a];
            }
        }
        __syncthreads();
    }

    // ---- write partials: Spart[b][chunk][h][d][e], Zpart[b][chunk][h][d] ----
    const size_t base = (((size_t)b * NCHUNK + chunk) * 4 + hh) * 32;
#pragma unroll
    for (int a = 0; a < 4; ++a) {
        float4 sv;
        sv.x = Sacc[a][0]; sv.y = Sacc[a][1]; sv.z = Sacc[a][2]; sv.w = Sacc[a][3];
        *(float4*)(Spart + (base + dr * 4 + a) * 32 + er * 4) = sv;
    }
    if (er == 0) {
#pragma unroll
        for (int a = 0; a < 4; ++a) Zpart[base + dr * 4 + a] = Zacc[a];
    }
}

__global__ __launch_bounds__(256, 1)
void la_k1_reduce(const float* __restrict__ Spart, const float* __restrict__ Zpart,
                  float* __restrict__ ctx)
{
    const int tid = threadIdx.x;
    const int b  = blockIdx.x >> 2;
    const int hh = blockIdx.x & 3;
    const int d  = tid >> 3;
    const int e0 = (tid & 7) << 2;
    float sx = 0.f, sy = 0.f, sz = 0.f, sw = 0.f, z = 0.f;
    for (int ch = 0; ch < NCHUNK; ++ch) {
        const size_t base = (((size_t)b * NCHUNK + ch) * 4 + hh) * 32 + d;
        const float4 v = *(const float4*)(Spart + base * 32 + e0);
        sx += v.x; sy += v.y; sz += v.z; sw += v.w;
        z += Zpart[base];
    }
    const float inv = 1.0f / (z * 16384.0f);
    float4 r; r.x = sx * inv; r.y = sy * inv; r.z = sz * inv; r.w = sw * inv;
    *(float4*)(ctx + ((((size_t)b * 4 + hh) * 32 + d) << 5) + e0) = r;
}

__global__ __launch_bounds__(256, 2)
void la_k2(const float* __restrict__ x, const float* __restrict__ Wqkv,
           const float* __restrict__ Wout, const float* __restrict__ bout,
           const float* __restrict__ g, const float* __restrict__ ctx,
           float* __restrict__ out)
{
    __shared__ float smem[2 * 8320];           // 66.6 KB -> 2 blocks/CU
    float* xs = smem;                          // [c][p] stride 65; later reused as out tile
    float* qs = smem + 8320;                   // q_s [row][p] stride 65; tail reused for LN

    const int tid = threadIdx.x;
    const int b     = blockIdx.y;
    const int chunk = blockIdx.x;
    const int p0 = chunk * TP;
    const int og = tid >> 4;
    const int pg = tid & 15;

    // ---- load x tile ----
#pragma unroll
    for (int i = 0; i < 8; ++i) {
        const int idx = tid + 256 * i;
        const int c  = idx >> 4;
        const int p4 = (idx & 15) << 2;
        const float4 v = *(const float4*)(x + ((size_t)b * 128 + c) * 16384 + p0 + p4);
        float* dst = &xs[c * 65 + p4];
        dst[0] = v.x; dst[1] = v.y; dst[2] = v.z; dst[3] = v.w;
    }
    __syncthreads();

    // ---- q GEMM: rows 0..127 of Wqkv -> qs ----
    {
        float acc[8][4];
#pragma unroll
        for (int j = 0; j < 8; ++j)
#pragma unroll
            for (int i = 0; i < 4; ++i) acc[j][i] = 0.f;
#pragma unroll 4
        for (int c = 0; c < 128; c += 4) {
            float4 w[8];
#pragma unroll
            for (int j = 0; j < 8; ++j)
                w[j] = *(const float4*)(Wqkv + (og * 8 + j) * 128 + c);
            float xv[4][4];
#pragma unroll
            for (int i = 0; i < 4; ++i)
#pragma unroll
                for (int cc = 0; cc < 4; ++cc)
                    xv[i][cc] = xs[(c + cc) * 65 + pg * 4 + i];
#pragma unroll
            for (int j = 0; j < 8; ++j)
#pragma unroll
                for (int i = 0; i < 4; ++i)
                    acc[j][i] += w[j].x * xv[i][0] + w[j].y * xv[i][1]
                               + w[j].z * xv[i][2] + w[j].w * xv[i][3];
        }
#pragma unroll
        for (int j = 0; j < 8; ++j)
#pragma unroll
            for (int i = 0; i < 4; ++i)
                qs[(og * 8 + j) * 65 + pg * 4 + i] = acc[j][i];
    }
    __syncthreads();

    // ---- softmax over d per (position, head), * scale ----
    {
        const int p  = tid & 63;
        const int sh = tid >> 6;
        float v[32];
        float m = -1e30f;
#pragma unroll
        for (int d = 0; d < 32; ++d) {
            v[d] = qs[(sh * 32 + d) * 65 + p];
            m = fmaxf(m, v[d]);
        }
        float s = 0.f;
#pragma unroll
        for (int d = 0; d < 32; ++d) { v[d] = expf(v[d] - m); s += v[d]; }
        const float inv = 0.17677669529663687f / s;   // scale = 32^-0.5
#pragma unroll
        for (int d = 0; d < 32; ++d)
            qs[(sh * 32 + d) * 65 + p] = v[d] * inv;
    }
    __syncthreads();

    // ---- out[e][p] = sum_d ctx[h][d][e] * q_s[h*32+d][p]  (overwrite xs) ----
    {
        float acc[8][4];
#pragma unroll
        for (int j = 0; j < 8; ++j)
#pragma unroll
            for (int i = 0; i < 4; ++i) acc[j][i] = 0.f;
        const int sh = og >> 2;
        const int e_base = (og & 3) * 8;
        const float* ctxh = ctx + (((size_t)b * 4 + sh) << 10);
#pragma unroll 4
        for (int d = 0; d < 32; ++d) {
            const float4 c0 = *(const float4*)(ctxh + d * 32 + e_base);
            const float4 c1 = *(const float4*)(ctxh + d * 32 + e_base + 4);
            float qv[4];
#pragma unroll
            for (int i = 0; i < 4; ++i)
                qv[i] = qs[(sh * 32 + d) * 65 + pg * 4 + i];
#pragma unroll
            for (int i = 0; i < 4; ++i) {
                acc[0][i] += c0.x * qv[i];
                acc[1][i] += c0.y * qv[i];
                acc[2][i] += c0.z * qv[i];
                acc[3][i] += c0.w * qv[i];
                acc[4][i] += c1.x * qv[i];
                acc[5][i] += c1.y * qv[i];
                acc[6][i] += c1.z * qv[i];
                acc[7][i] += c1.w * qv[i];
            }
        }
#pragma unroll
        for (int j = 0; j < 8; ++j)
#pragma unroll
            for (int i = 0; i < 4; ++i)
                xs[(og * 8 + j) * 65 + pg * 4 + i] = acc[j][i];
    }
    __syncthreads();

    // ---- y = Wout * out + bout ----
    float acc[8][4];
#pragma unroll
    for (int j = 0; j < 8; ++j)
#pragma unroll
        for (int i = 0; i < 4; ++i) acc[j][i] = 0.f;
#pragma unroll 4
    for (int c = 0; c < 128; c += 4) {
        float4 w[8];
#pragma unroll
        for (int j = 0; j < 8; ++j)
            w[j] = *(const float4*)(Wout + (og * 8 + j) * 128 + c);
        float xv[4][4];
#pragma unroll
        for (int i = 0; i < 4; ++i)
#pragma unroll
            for (int cc = 0; cc < 4; ++cc)
                xv[i][cc] = xs[(c + cc) * 65 + pg * 4 + i];
#pragma unroll
        for (int j = 0; j < 8; ++j)
#pragma unroll
            for (int i = 0; i < 4; ++i)
                acc[j][i] += w[j].x * xv[i][0] + w[j].y * xv[i][1]
                           + w[j].z * xv[i][2] + w[j].w * xv[i][3];
    }
#pragma unroll
    for (int j = 0; j < 8; ++j) {
        const float bo = bout[og * 8 + j];
#pragma unroll
        for (int i = 0; i < 4; ++i) acc[j][i] += bo;
    }

    // ---- LayerNorm over the 128 channels (two-pass), then * g, write ----
    float* red   = qs;              // [64][17]
    float* smean = qs + 64 * 17;    // [64]
    float* srstd = smean + 64;      // [64]
    // all qs readers finished at the post-out-phase barrier
#pragma unroll
    for (int i = 0; i < 4; ++i) {
        float ps = 0.f;
#pragma unroll
        for (int j = 0; j < 8; ++j) ps += acc[j][i];
        red[(pg * 4 + i) * 17 + og] = ps;
    }
    __syncthreads();
    if (tid < 64) {
        float ssum = 0.f;
#pragma unroll
        for (int o = 0; o < 16; ++o) ssum += red[tid * 17 + o];
        smean[tid] = ssum * (1.0f / 128.0f);
    }
    __syncthreads();
    float mn[4];
#pragma unroll
    for (int i = 0; i < 4; ++i) mn[i] = smean[pg * 4 + i];
#pragma unroll
    for (int i = 0; i < 4; ++i) {
        float ps = 0.f;
#pragma unroll
        for (int j = 0; j < 8; ++j) {
            const float d = acc[j][i] - mn[i];
            ps += d * d;
        }
        red[(pg * 4 + i) * 17 + og] = ps;
    }
    __syncthreads();
    if (tid < 64) {
        float ssum = 0.f;
#pragma unroll
        for (int o = 0; o < 16; ++o) ssum += red[tid * 17 + o];
        srstd[tid] = 1.0f / sqrtf(ssum * (1.0f / 128.0f) + 1e-5f);
    }
    __syncthreads();
    float rs[4];
#pragma unroll
    for (int i = 0; i < 4; ++i) rs[i] = srstd[pg * 4 + i];
#pragma unroll
    for (int j = 0; j < 8; ++j) {
        const float gg = g[og * 8 + j];
        float4 o4;
        o4.x = (acc[j][0] - mn[0]) * rs[0] * gg;
        o4.y = (acc[j][1] - mn[1]) * rs[1] * gg;
        o4.z = (acc[j][2] - mn[2]) * rs[2] * gg;
        o4.w = (acc[j][3] - mn[3]) * rs[3] * gg;
        *(float4*)(out + ((size_t)b * 128 + og * 8 + j) * 16384 + p0 + pg * 4) = o4;
    }
}

extern "C" void kernel_launch(void* const* d_in, const int* in_sizes, int n_in,
                              void* d_out, int out_size, void* d_ws, size_t ws_size,
                              hipStream_t stream) {
    const float* x    = (const float*)d_in[0];
    const float* Wqkv = (const float*)d_in[1];
    const float* Wout = (const float*)d_in[2];
    const float* bout = (const float*)d_in[3];
    const float* g    = (const float*)d_in[4];
    float* out = (float*)d_out;

    float* Spart = (float*)d_ws;                              // 32*64*4*32*32 = 8388608 f
    float* Zpart = Spart + (size_t)32 * NCHUNK * 4 * 32 * 32; // 32*64*4*32   = 262144 f
    float* ctx   = Zpart + (size_t)32 * NCHUNK * 4 * 32;      // 32*4*32*32   = 131072 f
    (void)in_sizes; (void)n_in; (void)out_size; (void)ws_size;

    la_k1<<<dim3(NCHUNK, 32), 256, 0, stream>>>(x, Wqkv, Spart, Zpart);
    la_k1_reduce<<<dim3(128), 256, 0, stream>>>(Spart, Zpart, ctx);
    la_k2<<<dim3(256, 32), 256, 0, stream>>>(x, Wqkv, Wout, bout, g, ctx, out);
}

// Round 3
// 1351.061 us; speedup vs baseline: 1.1043x; 1.1043x over previous
//
#include <hip/hip_runtime.h>
#include <math.h>

// LinearAttention: b=32, c=128, h=w=128 (n=16384), heads=4, dim_head=32, fp32.
//
// K1:  per (b, chunk): 4 tiles x 64 positions. x tile -> LDS (stride 64);
//      k,v GEMMs kept in registers; exp(k), v written to skewed LDS buffers
//      (overlapping the dead x region -> 69.9KB total -> 2 blocks/CU);
//      partial S[h][d][e] = sum_p exp(k[d,p]) * v[e,p]; Z via register partials.
// K1b: ctx[b][h][d][e] = (sum_ch S) / ((sum_ch Z) * n)
// K2:  recompute q, per-position softmax over d (*scale), out = ctx^T q_s,
//      y = Wout*out + bout, LayerNorm(channel) * g.

#define TP 64
#define NCHUNK 64

// skewed k/v layout: addr(row,p) = row*68 + 4*(7 - ((row>>2)&7)) + p
// DESCENDING skew: consecutive 4-row groups drop skew by exactly the 4 spare
// floats (gap >= 1 float at every boundary; the 0->28 wrap moves the next group
// later). Max addr = 127*68+63 = 8699 < 8736. Float4 writes canonical;
// S-phase read bank-quads = (12*dr + const) mod 32 -> 8 distinct -> conflict-free.
__device__ __forceinline__ int kvaddr(int row, int p) {
    return row * 68 + ((7 - ((row >> 2) & 7)) << 2) + p;
}

__global__ __launch_bounds__(256, 2)
void la_k1(const float* __restrict__ x, const float* __restrict__ Wqkv,
           float* __restrict__ Spart, float* __restrict__ Zpart)
{
    __shared__ float smem[2 * 8736];   // 69888 B -> 2 blocks/CU
    float* xs = smem;                  // [c][64] (overlaps ek region)
    float* ek = smem;                  // skewed [128 rows]
    float* vb = smem + 8736;           // skewed [128 rows]

    const int tid = threadIdx.x;
    const int b = blockIdx.y, chunk = blockIdx.x;
    const int og = tid >> 4, pg = tid & 15;
    const int hh = tid >> 6;
    const int dr = (tid >> 3) & 7;
    const int er = tid & 7;

    float Sacc[4][4];
#pragma unroll
    for (int a = 0; a < 4; ++a)
#pragma unroll
        for (int e = 0; e < 4; ++e) Sacc[a][e] = 0.f;
    float zreg[8];
#pragma unroll
    for (int j = 0; j < 8; ++j) zreg[j] = 0.f;

    float ka[8][4], va[8][4];

    for (int t = 0; t < 4; ++t) {
        const int p0 = (chunk * 4 + t) * TP;
        const float* xb = x + (size_t)b * 128 * 16384 + p0;
        // ---- stage x -> xs [c][64] (lane-linear, conflict-free) ----
#pragma unroll
        for (int i = 0; i < 8; ++i) {
            const int idx = tid + 256 * i;
            const int c  = idx >> 4;
            const int p4 = (idx & 15) << 2;
            const float4 v = *(const float4*)(xb + (size_t)c * 16384 + p4);
            *(float4*)(&xs[c * 64 + p4]) = v;
        }
        __syncthreads();

        // ---- K GEMM (Wqkv rows 128..255) -> ka, then exp ----
        {
#pragma unroll
            for (int j = 0; j < 8; ++j)
#pragma unroll
                for (int i = 0; i < 4; ++i) ka[j][i] = 0.f;
#pragma unroll 4
            for (int c = 0; c < 128; c += 4) {
                float4 w[8];
#pragma unroll
                for (int j = 0; j < 8; ++j)
                    w[j] = *(const float4*)(Wqkv + (128 + og * 8 + j) * 128 + c);
                float4 xv[4];
#pragma unroll
                for (int cc = 0; cc < 4; ++cc)
                    xv[cc] = *(const float4*)(&xs[(c + cc) * 64 + pg * 4]);
#pragma unroll
                for (int j = 0; j < 8; ++j) {
                    ka[j][0] += w[j].x * xv[0].x + w[j].y * xv[1].x + w[j].z * xv[2].x + w[j].w * xv[3].x;
                    ka[j][1] += w[j].x * xv[0].y + w[j].y * xv[1].y + w[j].z * xv[2].y + w[j].w * xv[3].y;
                    ka[j][2] += w[j].x * xv[0].z + w[j].y * xv[1].z + w[j].z * xv[2].z + w[j].w * xv[3].z;
                    ka[j][3] += w[j].x * xv[0].w + w[j].y * xv[1].w + w[j].z * xv[2].w + w[j].w * xv[3].w;
                }
            }
#pragma unroll
            for (int j = 0; j < 8; ++j)
#pragma unroll
                for (int i = 0; i < 4; ++i) ka[j][i] = expf(ka[j][i]);
            // Z partials (per-row, per-pg) accumulate in registers
#pragma unroll
            for (int j = 0; j < 8; ++j)
                zreg[j] += (ka[j][0] + ka[j][1]) + (ka[j][2] + ka[j][3]);
        }

        // ---- V GEMM (Wqkv rows 256..383) -> va ----
        {
#pragma unroll
            for (int j = 0; j < 8; ++j)
#pragma unroll
                for (int i = 0; i < 4; ++i) va[j][i] = 0.f;
#pragma unroll 4
            for (int c = 0; c < 128; c += 4) {
                float4 w[8];
#pragma unroll
                for (int j = 0; j < 8; ++j)
                    w[j] = *(const float4*)(Wqkv + (256 + og * 8 + j) * 128 + c);
                float4 xv[4];
#pragma unroll
                for (int cc = 0; cc < 4; ++cc)
                    xv[cc] = *(const float4*)(&xs[(c + cc) * 64 + pg * 4]);
#pragma unroll
                for (int j = 0; j < 8; ++j) {
                    va[j][0] += w[j].x * xv[0].x + w[j].y * xv[1].x + w[j].z * xv[2].x + w[j].w * xv[3].x;
                    va[j][1] += w[j].x * xv[0].y + w[j].y * xv[1].y + w[j].z * xv[2].y + w[j].w * xv[3].y;
                    va[j][2] += w[j].x * xv[0].z + w[j].y * xv[1].z + w[j].z * xv[2].z + w[j].w * xv[3].z;
                    va[j][3] += w[j].x * xv[0].w + w[j].y * xv[1].w + w[j].z * xv[2].w + w[j].w * xv[3].w;
                }
            }
        }
        // v region is disjoint from xs; prior S-phase readers done (barrier at loop end)
#pragma unroll
        for (int j = 0; j < 8; ++j) {
            float4 w4; w4.x = va[j][0]; w4.y = va[j][1]; w4.z = va[j][2]; w4.w = va[j][3];
            *(float4*)(&vb[kvaddr(og * 8 + j, pg * 4)]) = w4;
        }
        __syncthreads();   // all GEMM reads of xs done -> ek may overwrite xs
#pragma unroll
        for (int j = 0; j < 8; ++j) {
            float4 w4; w4.x = ka[j][0]; w4.y = ka[j][1]; w4.z = ka[j][2]; w4.w = ka[j][3];
            *(float4*)(&ek[kvaddr(og * 8 + j, pg * 4)]) = w4;
        }
        __syncthreads();

        // ---- S accumulation: S[4dr+a][4er+eo] += sum_p ek*v ----
        {
            const int ekbase = kvaddr(hh * 32 + 4 * dr, 0);
            const int vbase  = kvaddr(hh * 32 + 4 * er, 0);
#pragma unroll 4
            for (int q = 0; q < 16; ++q) {
                float4 e4[4], v4[4];
#pragma unroll
                for (int a = 0; a < 4; ++a)
                    e4[a] = *(const float4*)(&ek[ekbase + a * 68 + q * 4]);
#pragma unroll
                for (int eo = 0; eo < 4; ++eo)
                    v4[eo] = *(const float4*)(&vb[vbase + eo * 68 + q * 4]);
#pragma unroll
                for (int a = 0; a < 4; ++a)
#pragma unroll
                    for (int eo = 0; eo < 4; ++eo)
                        Sacc[a][eo] += e4[a].x * v4[eo].x + e4[a].y * v4[eo].y
                                     + e4[a].z * v4[eo].z + e4[a].w * v4[eo].w;
            }
        }
        __syncthreads();   // protect ek/vb before next tile's xs staging
    }

    // ---- write S partials ----
    const size_t base = (((size_t)b * NCHUNK + chunk) * 4 + hh) * 32;
#pragma unroll
    for (int a = 0; a < 4; ++a) {
        float4 sv; sv.x = Sacc[a][0]; sv.y = Sacc[a][1]; sv.z = Sacc[a][2]; sv.w = Sacc[a][3];
        *(float4*)(Spart + (base + 4 * dr + a) * 32 + 4 * er) = sv;
    }

    // ---- Z block-reduce: zreg[j] partials over 16 pg groups ----
    float* zred = smem;   // [128][17], S phase done (barrier above)
#pragma unroll
    for (int j = 0; j < 8; ++j)
        zred[(og * 8 + j) * 17 + pg] = zreg[j];
    __syncthreads();
    if (tid < 128) {
        float zs = 0.f;
#pragma unroll
        for (int p = 0; p < 16; ++p) zs += zred[tid * 17 + p];
        Zpart[((size_t)b * NCHUNK + chunk) * 128 + tid] = zs;
    }
}

__global__ __launch_bounds__(256, 1)
void la_k1_reduce(const float* __restrict__ Spart, const float* __restrict__ Zpart,
                  float* __restrict__ ctx)
{
    const int tid = threadIdx.x;
    const int b  = blockIdx.x >> 2;
    const int hh = blockIdx.x & 3;
    const int d  = tid >> 3;
    const int e0 = (tid & 7) << 2;
    float sx = 0.f, sy = 0.f, sz = 0.f, sw = 0.f, z = 0.f;
    for (int ch = 0; ch < NCHUNK; ++ch) {
        const size_t base = (((size_t)b * NCHUNK + ch) * 4 + hh) * 32 + d;
        const float4 v = *(const float4*)(Spart + base * 32 + e0);
        sx += v.x; sy += v.y; sz += v.z; sw += v.w;
        z += Zpart[base];
    }
    const float inv = 1.0f / (z * 16384.0f);
    float4 r; r.x = sx * inv; r.y = sy * inv; r.z = sz * inv; r.w = sw * inv;
    *(float4*)(ctx + ((((size_t)b * 4 + hh) * 32 + d) << 5) + e0) = r;
}

__global__ __launch_bounds__(256, 2)
void la_k2(const float* __restrict__ x, const float* __restrict__ Wqkv,
           const float* __restrict__ Wout, const float* __restrict__ bout,
           const float* __restrict__ g, const float* __restrict__ ctx,
           float* __restrict__ out)
{
    __shared__ float smem[8192 + 8704];   // 67584 B -> 2 blocks/CU
    float* xs = smem;                     // [c][64]; later the out tile
    float* qs = smem + 8192;              // [row][68]; tail reused for LN scratch

    const int tid = threadIdx.x;
    const int b     = blockIdx.y;
    const int chunk = blockIdx.x;
    const int p0 = chunk * TP;
    const int og = tid >> 4;
    const int pg = tid & 15;

    // ---- stage x ----
#pragma unroll
    for (int i = 0; i < 8; ++i) {
        const int idx = tid + 256 * i;
        const int c  = idx >> 4;
        const int p4 = (idx & 15) << 2;
        const float4 v = *(const float4*)(x + ((size_t)b * 128 + c) * 16384 + p0 + p4);
        *(float4*)(&xs[c * 64 + p4]) = v;
    }
    __syncthreads();

    // ---- q GEMM (Wqkv rows 0..127) -> qs ----
    {
        float acc[8][4];
#pragma unroll
        for (int j = 0; j < 8; ++j)
#pragma unroll
            for (int i = 0; i < 4; ++i) acc[j][i] = 0.f;
#pragma unroll 4
        for (int c = 0; c < 128; c += 4) {
            float4 w[8];
#pragma unroll
            for (int j = 0; j < 8; ++j)
                w[j] = *(const float4*)(Wqkv + (og * 8 + j) * 128 + c);
            float4 xv[4];
#pragma unroll
            for (int cc = 0; cc < 4; ++cc)
                xv[cc] = *(const float4*)(&xs[(c + cc) * 64 + pg * 4]);
#pragma unroll
            for (int j = 0; j < 8; ++j) {
                acc[j][0] += w[j].x * xv[0].x + w[j].y * xv[1].x + w[j].z * xv[2].x + w[j].w * xv[3].x;
                acc[j][1] += w[j].x * xv[0].y + w[j].y * xv[1].y + w[j].z * xv[2].y + w[j].w * xv[3].y;
                acc[j][2] += w[j].x * xv[0].z + w[j].y * xv[1].z + w[j].z * xv[2].z + w[j].w * xv[3].z;
                acc[j][3] += w[j].x * xv[0].w + w[j].y * xv[1].w + w[j].z * xv[2].w + w[j].w * xv[3].w;
            }
        }
#pragma unroll
        for (int j = 0; j < 8; ++j) {
            float4 w4; w4.x = acc[j][0]; w4.y = acc[j][1]; w4.z = acc[j][2]; w4.w = acc[j][3];
            *(float4*)(&qs[(og * 8 + j) * 68 + pg * 4]) = w4;
        }
    }
    __syncthreads();

    // ---- softmax over d per (position, head), * scale ----
    {
        const int p  = tid & 63;
        const int sh = tid >> 6;
        float v[32];
        float m = -1e30f;
#pragma unroll
        for (int d = 0; d < 32; ++d) {
            v[d] = qs[(sh * 32 + d) * 68 + p];
            m = fmaxf(m, v[d]);
        }
        float s = 0.f;
#pragma unroll
        for (int d = 0; d < 32; ++d) { v[d] = expf(v[d] - m); s += v[d]; }
        const float inv = 0.17677669529663687f / s;   // 32^-0.5 / s
#pragma unroll
        for (int d = 0; d < 32; ++d)
            qs[(sh * 32 + d) * 68 + p] = v[d] * inv;
    }
    __syncthreads();

    // ---- out[e][p] = sum_d ctx[h][d][e] * q_s[h*32+d][p] -> xs ----
    {
        float acc[8][4];
#pragma unroll
        for (int j = 0; j < 8; ++j)
#pragma unroll
            for (int i = 0; i < 4; ++i) acc[j][i] = 0.f;
        const int sh = og >> 2;
        const int e_base = (og & 3) * 8;
        const float* ctxh = ctx + (((size_t)b * 4 + sh) << 10);
#pragma unroll 4
        for (int d = 0; d < 32; ++d) {
            const float4 c0 = *(const float4*)(ctxh + d * 32 + e_base);
            const float4 c1 = *(const float4*)(ctxh + d * 32 + e_base + 4);
            const float4 qv = *(const float4*)(&qs[(sh * 32 + d) * 68 + pg * 4]);
            const float q0 = qv.x, q1 = qv.y, q2 = qv.z, q3 = qv.w;
            acc[0][0] += c0.x * q0; acc[0][1] += c0.x * q1; acc[0][2] += c0.x * q2; acc[0][3] += c0.x * q3;
            acc[1][0] += c0.y * q0; acc[1][1] += c0.y * q1; acc[1][2] += c0.y * q2; acc[1][3] += c0.y * q3;
            acc[2][0] += c0.z * q0; acc[2][1] += c0.z * q1; acc[2][2] += c0.z * q2; acc[2][3] += c0.z * q3;
            acc[3][0] += c0.w * q0; acc[3][1] += c0.w * q1; acc[3][2] += c0.w * q2; acc[3][3] += c0.w * q3;
            acc[4][0] += c1.x * q0; acc[4][1] += c1.x * q1; acc[4][2] += c1.x * q2; acc[4][3] += c1.x * q3;
            acc[5][0] += c1.y * q0; acc[5][1] += c1.y * q1; acc[5][2] += c1.y * q2; acc[5][3] += c1.y * q3;
            acc[6][0] += c1.z * q0; acc[6][1] += c1.z * q1; acc[6][2] += c1.z * q2; acc[6][3] += c1.z * q3;
            acc[7][0] += c1.w * q0; acc[7][1] += c1.w * q1; acc[7][2] += c1.w * q2; acc[7][3] += c1.w * q3;
        }
#pragma unroll
        for (int j = 0; j < 8; ++j) {
            float4 w4; w4.x = acc[j][0]; w4.y = acc[j][1]; w4.z = acc[j][2]; w4.w = acc[j][3];
            *(float4*)(&xs[(og * 8 + j) * 64 + pg * 4]) = w4;
        }
    }
    __syncthreads();

    // ---- y = Wout * out + bout ----
    float acc[8][4];
#pragma unroll
    for (int j = 0; j < 8; ++j)
#pragma unroll
        for (int i = 0; i < 4; ++i) acc[j][i] = 0.f;
#pragma unroll 4
    for (int c = 0; c < 128; c += 4) {
        float4 w[8];
#pragma unroll
        for (int j = 0; j < 8; ++j)
            w[j] = *(const float4*)(Wout + (og * 8 + j) * 128 + c);
        float4 xv[4];
#pragma unroll
        for (int cc = 0; cc < 4; ++cc)
            xv[cc] = *(const float4*)(&xs[(c + cc) * 64 + pg * 4]);
#pragma unroll
        for (int j = 0; j < 8; ++j) {
            acc[j][0] += w[j].x * xv[0].x + w[j].y * xv[1].x + w[j].z * xv[2].x + w[j].w * xv[3].x;
            acc[j][1] += w[j].x * xv[0].y + w[j].y * xv[1].y + w[j].z * xv[2].y + w[j].w * xv[3].y;
            acc[j][2] += w[j].x * xv[0].z + w[j].y * xv[1].z + w[j].z * xv[2].z + w[j].w * xv[3].z;
            acc[j][3] += w[j].x * xv[0].w + w[j].y * xv[1].w + w[j].z * xv[2].w + w[j].w * xv[3].w;
        }
    }
#pragma unroll
    for (int j = 0; j < 8; ++j) {
        const float bo = bout[og * 8 + j];
#pragma unroll
        for (int i = 0; i < 4; ++i) acc[j][i] += bo;
    }

    // ---- LayerNorm (two-pass) then * g, write ----
    float* red   = qs;              // [64][17]
    float* smean = qs + 64 * 17;
    float* srstd = smean + 64;
#pragma unroll
    for (int i = 0; i < 4; ++i) {
        float ps = 0.f;
#pragma unroll
        for (int j = 0; j < 8; ++j) ps += acc[j][i];
        red[(pg * 4 + i) * 17 + og] = ps;
    }
    __syncthreads();
    if (tid < 64) {
        float ssum = 0.f;
#pragma unroll
        for (int o = 0; o < 16; ++o) ssum += red[tid * 17 + o];
        smean[tid] = ssum * (1.0f / 128.0f);
    }
    __syncthreads();
    float mn[4];
#pragma unroll
    for (int i = 0; i < 4; ++i) mn[i] = smean[pg * 4 + i];
#pragma unroll
    for (int i = 0; i < 4; ++i) {
        float ps = 0.f;
#pragma unroll
        for (int j = 0; j < 8; ++j) {
            const float d = acc[j][i] - mn[i];
            ps += d * d;
        }
        red[(pg * 4 + i) * 17 + og] = ps;
    }
    __syncthreads();
    if (tid < 64) {
        float ssum = 0.f;
#pragma unroll
        for (int o = 0; o < 16; ++o) ssum += red[tid * 17 + o];
        srstd[tid] = 1.0f / sqrtf(ssum * (1.0f / 128.0f) + 1e-5f);
    }
    __syncthreads();
    float rs[4];
#pragma unroll
    for (int i = 0; i < 4; ++i) rs[i] = srstd[pg * 4 + i];
#pragma unroll
    for (int j = 0; j < 8; ++j) {
        const float gg = g[og * 8 + j];
        float4 o4;
        o4.x = (acc[j][0] - mn[0]) * rs[0] * gg;
        o4.y = (acc[j][1] - mn[1]) * rs[1] * gg;
        o4.z = (acc[j][2] - mn[2]) * rs[2] * gg;
        o4.w = (acc[j][3] - mn[3]) * rs[3] * gg;
        *(float4*)(out + ((size_t)b * 128 + og * 8 + j) * 16384 + p0 + pg * 4) = o4;
    }
}

extern "C" void kernel_launch(void* const* d_in, const int* in_sizes, int n_in,
                              void* d_out, int out_size, void* d_ws, size_t ws_size,
                              hipStream_t stream) {
    const float* x    = (const float*)d_in[0];
    const float* Wqkv = (const float*)d_in[1];
    const float* Wout = (const float*)d_in[2];
    const float* bout = (const float*)d_in[3];
    const float* g    = (const float*)d_in[4];
    float* out = (float*)d_out;

    float* Spart = (float*)d_ws;                              // 32*64*4*32*32 floats
    float* Zpart = Spart + (size_t)32 * NCHUNK * 4 * 32 * 32; // 32*64*128 floats
    float* ctx   = Zpart + (size_t)32 * NCHUNK * 4 * 32;      // 32*4*32*32 floats
    (void)in_sizes; (void)n_in; (void)out_size; (void)ws_size;

    la_k1<<<dim3(NCHUNK, 32), 256, 0, stream>>>(x, Wqkv, Spart, Zpart);
    la_k1_reduce<<<dim3(128), 256, 0, stream>>>(Spart, Zpart, ctx);
    la_k2<<<dim3(256, 32), 256, 0, stream>>>(x, Wqkv, Wout, bout, g, ctx, out);
}

// Round 4
// 1223.243 us; speedup vs baseline: 1.2196x; 1.1045x over previous
//
#include <hip/hip_runtime.h>
#include <math.h>

// LinearAttention: b=32, c=128, h=w=128 (n=16384), heads=4, dim_head=32.
// K1 rewritten with split-bf16 MFMA (3-term: AhBh+AhBl+AlBh, fp32 acc):
//   prep: Wqkv -> Wh/Wl bf16 in ws.
//   K1: per (b,chunk), 4 tiles x 64 pos. Stage x -> xTh/xTl bf16 [64p][128c]
//       (in-register 4x4 transpose, XOR-swizzled). k/v GEMM on MFMA 16x16x32;
//       exp(k), v packed (h|l<<16) u32 rows [128r][64p]; S[d][e] per head also
//       MFMA; Z via h+l reads + shfl pair-reduce.
//   K1b: ctx = (sum S) / ((sum Z) * n)     [unchanged]
//   K2:  fp32 VALU (unchanged, known-good).

#define TP 64
#define NCHUNK 64

typedef __attribute__((ext_vector_type(8))) short short8;
typedef __attribute__((ext_vector_type(4))) float f32x4;

__device__ __forceinline__ uint bf16r(float f) {
    uint u = __float_as_uint(f);
    return (u + 0x7FFFu + ((u >> 16) & 1u)) >> 16;   // RNE to bf16 (16-bit in low)
}
__device__ __forceinline__ float bf16f(uint h) { return __uint_as_float(h << 16); }
__device__ __forceinline__ uint2 bsplit(float f) {
    uint h = bf16r(f);
    float r = f - bf16f(h);
    return make_uint2(h, bf16r(r));
}
// 8 packed u32 (lo=h,hi=l) -> bf16x8 of lo / hi halves
__device__ __forceinline__ short8 lo8(uint4 a, uint4 b) {
    uint4 r;
    r.x = (a.x & 0xFFFFu) | (a.y << 16);
    r.y = (a.z & 0xFFFFu) | (a.w << 16);
    r.z = (b.x & 0xFFFFu) | (b.y << 16);
    r.w = (b.z & 0xFFFFu) | (b.w << 16);
    return __builtin_bit_cast(short8, r);
}
__device__ __forceinline__ short8 hi8(uint4 a, uint4 b) {
    uint4 r;
    r.x = (a.x >> 16) | (a.y & 0xFFFF0000u);
    r.y = (a.z >> 16) | (a.w & 0xFFFF0000u);
    r.z = (b.x >> 16) | (b.y & 0xFFFF0000u);
    r.w = (b.z >> 16) | (b.w & 0xFFFF0000u);
    return __builtin_bit_cast(short8, r);
}

__global__ __launch_bounds__(256)
void wsplit(const float* __restrict__ W, ushort* __restrict__ Wh,
            ushort* __restrict__ Wl, int n)
{
    const int base = (blockIdx.x * 256 + threadIdx.x) * 4;
    if (base + 3 < n) {
        const float4 f = *(const float4*)(W + base);
        const uint2 a = bsplit(f.x), b2 = bsplit(f.y), c = bsplit(f.z), d = bsplit(f.w);
        ushort4 hh; hh.x = (ushort)a.x; hh.y = (ushort)b2.x; hh.z = (ushort)c.x; hh.w = (ushort)d.x;
        ushort4 ll; ll.x = (ushort)a.y; ll.y = (ushort)b2.y; ll.z = (ushort)c.y; ll.w = (ushort)d.y;
        *(ushort4*)(Wh + base) = hh;
        *(ushort4*)(Wl + base) = ll;
    }
}

#define MFMA(A, B, C) __builtin_amdgcn_mfma_f32_16x16x32_bf16((A), (B), (C), 0, 0, 0)

__global__ __launch_bounds__(256, 2)
void la_k1(const float* __restrict__ x,
           const ushort* __restrict__ Wh, const ushort* __restrict__ Wl,
           float* __restrict__ Spart, float* __restrict__ Zpart)
{
    // bytes [0,16384):      xTh bf16 [64p][128c], byte = p*256 + 2c ^ ((p&7)<<4)
    // bytes [16384,32768):  xTl
    // bytes [0,32768):      ekp u32 [128r][64p], byte = r*256 + 4p ^ ((r&7)<<4)  (after GEMM)
    // bytes [32768,65536):  vbp u32 [128r][64p]
    __shared__ __align__(16) char smb[65536];

    const int tid = threadIdx.x;
    const int b = blockIdx.y, chunk = blockIdx.x;
    const int w = tid >> 6, l = tid & 63;
    const int l15 = l & 15, lg = l >> 4;
    const int ch2 = w >> 1;        // col half (p 32*ch2..)
    const int rp  = w & 1;         // row-tile parity

    f32x4 s2[2][2];
#pragma unroll
    for (int i = 0; i < 2; ++i)
#pragma unroll
        for (int j = 0; j < 2; ++j) s2[i][j] = (f32x4){0.f, 0.f, 0.f, 0.f};
    float zacc = 0.f;

    for (int t = 0; t < 4; ++t) {
        const int p0 = (chunk * 4 + t) * TP;
        const float* xb = x + (size_t)b * 128 * 16384 + p0;

        // ---- stage x -> xTh/xTl (in-register 4x4 transpose, b64 writes) ----
        {
            const int j = tid & 15, g = tid >> 4;
            const int pb = j * 4;
#pragma unroll
            for (int u = 0; u < 2; ++u) {
                const int cb = g * 4 + u * 64;
                const float4 xv0 = *(const float4*)(xb + (size_t)(cb + 0) * 16384 + pb);
                const float4 xv1 = *(const float4*)(xb + (size_t)(cb + 1) * 16384 + pb);
                const float4 xv2 = *(const float4*)(xb + (size_t)(cb + 2) * 16384 + pb);
                const float4 xv3 = *(const float4*)(xb + (size_t)(cb + 3) * 16384 + pb);
                float rc[4][4];
                rc[0][0] = xv0.x; rc[0][1] = xv0.y; rc[0][2] = xv0.z; rc[0][3] = xv0.w;
                rc[1][0] = xv1.x; rc[1][1] = xv1.y; rc[1][2] = xv1.z; rc[1][3] = xv1.w;
                rc[2][0] = xv2.x; rc[2][1] = xv2.y; rc[2][2] = xv2.z; rc[2][3] = xv2.w;
                rc[3][0] = xv3.x; rc[3][1] = xv3.y; rc[3][2] = xv3.z; rc[3][3] = xv3.w;
#pragma unroll
                for (int pp = 0; pp < 4; ++pp) {
                    const uint2 s0 = bsplit(rc[0][pp]);
                    const uint2 s1 = bsplit(rc[1][pp]);
                    const uint2 s2u = bsplit(rc[2][pp]);
                    const uint2 s3 = bsplit(rc[3][pp]);
                    const int p = pb + pp;
                    const int byt = (p * 256 + cb * 2) ^ ((p & 7) << 4);
                    *(uint2*)(&smb[byt])         = make_uint2(s0.x | (s1.x << 16), s2u.x | (s3.x << 16));
                    *(uint2*)(&smb[16384 + byt]) = make_uint2(s0.y | (s1.y << 16), s2u.y | (s3.y << 16));
                }
            }
        }
        __syncthreads();

        // ---- k/v GEMM: C[256 rows][64 p] via split-bf16 MFMA ----
        f32x4 acc[8][2];
#pragma unroll
        for (int rt = 0; rt < 8; ++rt)
#pragma unroll
            for (int ct = 0; ct < 2; ++ct) acc[rt][ct] = (f32x4){0.f, 0.f, 0.f, 0.f};

#pragma unroll
        for (int ks = 0; ks < 4; ++ks) {
            short8 Bh[2], Bl[2];
#pragma unroll
            for (int ct = 0; ct < 2; ++ct) {
                const int p = ch2 * 32 + ct * 16 + l15;
                const int byt = (p * 256 + (ks * 32 + lg * 8) * 2) ^ ((p & 7) << 4);
                Bh[ct] = *(const short8*)(&smb[byt]);
                Bl[ct] = *(const short8*)(&smb[16384 + byt]);
            }
#pragma unroll
            for (int rt = 0; rt < 8; ++rt) {
                const int T = rt * 2 + rp;                  // global row-tile 0..15
                const size_t aoff = (size_t)(128 + T * 16 + l15) * 128 + ks * 32 + lg * 8;
                const short8 Ah_ = *(const short8*)(Wh + aoff);
                const short8 Al_ = *(const short8*)(Wl + aoff);
#pragma unroll
                for (int ct = 0; ct < 2; ++ct) {
                    acc[rt][ct] = MFMA(Ah_, Bh[ct], acc[rt][ct]);
                    acc[rt][ct] = MFMA(Ah_, Bl[ct], acc[rt][ct]);
                    acc[rt][ct] = MFMA(Al_, Bh[ct], acc[rt][ct]);
                }
            }
        }
        __syncthreads();   // all xT reads done; ek may overwrite

        // ---- producer: exp(k)/v -> packed u32 rows ----
#pragma unroll
        for (int rt = 0; rt < 8; ++rt) {
            const int T = rt * 2 + rp;
            const bool isk = (T < 8);
            const int rbase = (T & 7) * 16 + lg * 4;
#pragma unroll
            for (int ct = 0; ct < 2; ++ct) {
                const int p = ch2 * 32 + ct * 16 + l15;
#pragma unroll
                for (int i = 0; i < 4; ++i) {
                    float val = acc[rt][ct][i];
                    if (isk) val = expf(val);
                    const int r = rbase + i;
                    const uint2 hl = bsplit(val);
                    const int byt = (r * 256 + p * 4) ^ ((r & 7) << 4);
                    *(uint*)(&smb[(isk ? 0 : 32768) + byt]) = hl.x | (hl.y << 16);
                }
            }
        }
        __syncthreads();

        // ---- S-phase MFMA: head w, S[32d][32e] += ek * v^T over 64 p ----
#pragma unroll
        for (int ks2 = 0; ks2 < 2; ++ks2) {
            const int pq = ks2 * 32 + lg * 8;
            short8 A2h[2], A2l[2], B2h[2], B2l[2];
#pragma unroll
            for (int rt2 = 0; rt2 < 2; ++rt2) {
                const int r = w * 32 + rt2 * 16 + l15;
                const int b0 = (r * 256 + pq * 4) ^ ((r & 7) << 4);
                const int b1 = (r * 256 + pq * 4 + 16) ^ ((r & 7) << 4);
                const uint4 q0 = *(const uint4*)(&smb[b0]);
                const uint4 q1 = *(const uint4*)(&smb[b1]);
                A2h[rt2] = lo8(q0, q1);
                A2l[rt2] = hi8(q0, q1);
                const uint4 r0 = *(const uint4*)(&smb[32768 + b0]);
                const uint4 r1 = *(const uint4*)(&smb[32768 + b1]);
                B2h[rt2] = lo8(r0, r1);
                B2l[rt2] = hi8(r0, r1);
            }
#pragma unroll
            for (int rt2 = 0; rt2 < 2; ++rt2)
#pragma unroll
                for (int ct2 = 0; ct2 < 2; ++ct2) {
                    s2[rt2][ct2] = MFMA(A2h[rt2], B2h[ct2], s2[rt2][ct2]);
                    s2[rt2][ct2] = MFMA(A2h[rt2], B2l[ct2], s2[rt2][ct2]);
                    s2[rt2][ct2] = MFMA(A2l[rt2], B2h[ct2], s2[rt2][ct2]);
                }
        }
        // ---- Z: per-row sum of exp(k) (h+l reconstruct) ----
        {
            const int r = tid >> 1;
            const int ph = (tid & 1) * 32;
            float zs = 0.f;
#pragma unroll
            for (int c = 0; c < 8; ++c) {
                const int byt = (r * 256 + (ph + c * 4) * 4) ^ ((r & 7) << 4);
                const uint4 q = *(const uint4*)(&smb[byt]);
                zs += bf16f(q.x & 0xFFFFu) + bf16f(q.x >> 16)
                    + bf16f(q.y & 0xFFFFu) + bf16f(q.y >> 16)
                    + bf16f(q.z & 0xFFFFu) + bf16f(q.z >> 16)
                    + bf16f(q.w & 0xFFFFu) + bf16f(q.w >> 16);
            }
            zacc += zs;
        }
        __syncthreads();   // ek/vb consumed; next tile may restage
    }

    // ---- write S partials: Spart[b][ch][head=w][d][e] ----
    const size_t sbase = (((size_t)b * NCHUNK + chunk) * 4 + w) * 1024;
#pragma unroll
    for (int rt2 = 0; rt2 < 2; ++rt2)
#pragma unroll
        for (int ct2 = 0; ct2 < 2; ++ct2)
#pragma unroll
            for (int i = 0; i < 4; ++i) {
                const int d = rt2 * 16 + lg * 4 + i;
                const int e = ct2 * 16 + l15;
                Spart[sbase + d * 32 + e] = s2[rt2][ct2][i];
            }
    // ---- Z: pair-reduce and write ----
    const float ztot = zacc + __shfl_xor(zacc, 1, 64);
    if ((tid & 1) == 0)
        Zpart[((size_t)b * NCHUNK + chunk) * 128 + (tid >> 1)] = ztot;
}

__global__ __launch_bounds__(256, 1)
void la_k1_reduce(const float* __restrict__ Spart, const float* __restrict__ Zpart,
                  float* __restrict__ ctx)
{
    const int tid = threadIdx.x;
    const int b  = blockIdx.x >> 2;
    const int hh = blockIdx.x & 3;
    const int d  = tid >> 3;
    const int e0 = (tid & 7) << 2;
    float sx = 0.f, sy = 0.f, sz = 0.f, sw = 0.f, z = 0.f;
    for (int ch = 0; ch < NCHUNK; ++ch) {
        const size_t base = (((size_t)b * NCHUNK + ch) * 4 + hh) * 32 + d;
        const float4 v = *(const float4*)(Spart + base * 32 + e0);
        sx += v.x; sy += v.y; sz += v.z; sw += v.w;
        z += Zpart[base];
    }
    const float inv = 1.0f / (z * 16384.0f);
    float4 r; r.x = sx * inv; r.y = sy * inv; r.z = sz * inv; r.w = sw * inv;
    *(float4*)(ctx + ((((size_t)b * 4 + hh) * 32 + d) << 5) + e0) = r;
}

__global__ __launch_bounds__(256, 2)
void la_k2(const float* __restrict__ x, const float* __restrict__ Wqkv,
           const float* __restrict__ Wout, const float* __restrict__ bout,
           const float* __restrict__ g, const float* __restrict__ ctx,
           float* __restrict__ out)
{
    __shared__ float smem[8192 + 8704];   // 67584 B -> 2 blocks/CU
    float* xs = smem;                     // [c][64]; later the out tile
    float* qs = smem + 8192;              // [row][68]; tail reused for LN scratch

    const int tid = threadIdx.x;
    const int b     = blockIdx.y;
    const int chunk = blockIdx.x;
    const int p0 = chunk * TP;
    const int og = tid >> 4;
    const int pg = tid & 15;

    // ---- stage x ----
#pragma unroll
    for (int i = 0; i < 8; ++i) {
        const int idx = tid + 256 * i;
        const int c  = idx >> 4;
        const int p4 = (idx & 15) << 2;
        const float4 v = *(const float4*)(x + ((size_t)b * 128 + c) * 16384 + p0 + p4);
        *(float4*)(&xs[c * 64 + p4]) = v;
    }
    __syncthreads();

    // ---- q GEMM (Wqkv rows 0..127) -> qs ----
    {
        float acc[8][4];
#pragma unroll
        for (int j = 0; j < 8; ++j)
#pragma unroll
            for (int i = 0; i < 4; ++i) acc[j][i] = 0.f;
#pragma unroll 4
        for (int c = 0; c < 128; c += 4) {
            float4 w[8];
#pragma unroll
            for (int j = 0; j < 8; ++j)
                w[j] = *(const float4*)(Wqkv + (og * 8 + j) * 128 + c);
            float4 xv[4];
#pragma unroll
            for (int cc = 0; cc < 4; ++cc)
                xv[cc] = *(const float4*)(&xs[(c + cc) * 64 + pg * 4]);
#pragma unroll
            for (int j = 0; j < 8; ++j) {
                acc[j][0] += w[j].x * xv[0].x + w[j].y * xv[1].x + w[j].z * xv[2].x + w[j].w * xv[3].x;
                acc[j][1] += w[j].x * xv[0].y + w[j].y * xv[1].y + w[j].z * xv[2].y + w[j].w * xv[3].y;
                acc[j][2] += w[j].x * xv[0].z + w[j].y * xv[1].z + w[j].z * xv[2].z + w[j].w * xv[3].z;
                acc[j][3] += w[j].x * xv[0].w + w[j].y * xv[1].w + w[j].z * xv[2].w + w[j].w * xv[3].w;
            }
        }
#pragma unroll
        for (int j = 0; j < 8; ++j) {
            float4 w4; w4.x = acc[j][0]; w4.y = acc[j][1]; w4.z = acc[j][2]; w4.w = acc[j][3];
            *(float4*)(&qs[(og * 8 + j) * 68 + pg * 4]) = w4;
        }
    }
    __syncthreads();

    // ---- softmax over d per (position, head), * scale ----
    {
        const int p  = tid & 63;
        const int sh = tid >> 6;
        float v[32];
        float m = -1e30f;
#pragma unroll
        for (int d = 0; d < 32; ++d) {
            v[d] = qs[(sh * 32 + d) * 68 + p];
            m = fmaxf(m, v[d]);
        }
        float s = 0.f;
#pragma unroll
        for (int d = 0; d < 32; ++d) { v[d] = expf(v[d] - m); s += v[d]; }
        const float inv = 0.17677669529663687f / s;   // 32^-0.5 / s
#pragma unroll
        for (int d = 0; d < 32; ++d)
            qs[(sh * 32 + d) * 68 + p] = v[d] * inv;
    }
    __syncthreads();

    // ---- out[e][p] = sum_d ctx[h][d][e] * q_s[h*32+d][p] -> xs ----
    {
        float acc[8][4];
#pragma unroll
        for (int j = 0; j < 8; ++j)
#pragma unroll
            for (int i = 0; i < 4; ++i) acc[j][i] = 0.f;
        const int sh = og >> 2;
        const int e_base = (og & 3) * 8;
        const float* ctxh = ctx + (((size_t)b * 4 + sh) << 10);
#pragma unroll 4
        for (int d = 0; d < 32; ++d) {
            const float4 c0 = *(const float4*)(ctxh + d * 32 + e_base);
            const float4 c1 = *(const float4*)(ctxh + d * 32 + e_base + 4);
            const float4 qv = *(const float4*)(&qs[(sh * 32 + d) * 68 + pg * 4]);
            const float q0 = qv.x, q1 = qv.y, q2 = qv.z, q3 = qv.w;
            acc[0][0] += c0.x * q0; acc[0][1] += c0.x * q1; acc[0][2] += c0.x * q2; acc[0][3] += c0.x * q3;
            acc[1][0] += c0.y * q0; acc[1][1] += c0.y * q1; acc[1][2] += c0.y * q2; acc[1][3] += c0.y * q3;
            acc[2][0] += c0.z * q0; acc[2][1] += c0.z * q1; acc[2][2] += c0.z * q2; acc[2][3] += c0.z * q3;
            acc[3][0] += c0.w * q0; acc[3][1] += c0.w * q1; acc[3][2] += c0.w * q2; acc[3][3] += c0.w * q3;
            acc[4][0] += c1.x * q0; acc[4][1] += c1.x * q1; acc[4][2] += c1.x * q2; acc[4][3] += c1.x * q3;
            acc[5][0] += c1.y * q0; acc[5][1] += c1.y * q1; acc[5][2] += c1.y * q2; acc[5][3] += c1.y * q3;
            acc[6][0] += c1.z * q0; acc[6][1] += c1.z * q1; acc[6][2] += c1.z * q2; acc[6][3] += c1.z * q3;
            acc[7][0] += c1.w * q0; acc[7][1] += c1.w * q1; acc[7][2] += c1.w * q2; acc[7][3] += c1.w * q3;
        }
#pragma unroll
        for (int j = 0; j < 8; ++j) {
            float4 w4; w4.x = acc[j][0]; w4.y = acc[j][1]; w4.z = acc[j][2]; w4.w = acc[j][3];
            *(float4*)(&xs[(og * 8 + j) * 64 + pg * 4]) = w4;
        }
    }
    __syncthreads();

    // ---- y = Wout * out + bout ----
    float acc[8][4];
#pragma unroll
    for (int j = 0; j < 8; ++j)
#pragma unroll
        for (int i = 0; i < 4; ++i) acc[j][i] = 0.f;
#pragma unroll 4
    for (int c = 0; c < 128; c += 4) {
        float4 w[8];
#pragma unroll
        for (int j = 0; j < 8; ++j)
            w[j] = *(const float4*)(Wout + (og * 8 + j) * 128 + c);
        float4 xv[4];
#pragma unroll
        for (int cc = 0; cc < 4; ++cc)
            xv[cc] = *(const float4*)(&xs[(c + cc) * 64 + pg * 4]);
#pragma unroll
        for (int j = 0; j < 8; ++j) {
            acc[j][0] += w[j].x * xv[0].x + w[j].y * xv[1].x + w[j].z * xv[2].x + w[j].w * xv[3].x;
            acc[j][1] += w[j].x * xv[0].y + w[j].y * xv[1].y + w[j].z * xv[2].y + w[j].w * xv[3].y;
            acc[j][2] += w[j].x * xv[0].z + w[j].y * xv[1].z + w[j].z * xv[2].z + w[j].w * xv[3].z;
            acc[j][3] += w[j].x * xv[0].w + w[j].y * xv[1].w + w[j].z * xv[2].w + w[j].w * xv[3].w;
        }
    }
#pragma unroll
    for (int j = 0; j < 8; ++j) {
        const float bo = bout[og * 8 + j];
#pragma unroll
        for (int i = 0; i < 4; ++i) acc[j][i] += bo;
    }

    // ---- LayerNorm (two-pass) then * g, write ----
    float* red   = qs;              // [64][17]
    float* smean = qs + 64 * 17;
    float* srstd = smean + 64;
#pragma unroll
    for (int i = 0; i < 4; ++i) {
        float ps = 0.f;
#pragma unroll
        for (int j = 0; j < 8; ++j) ps += acc[j][i];
        red[(pg * 4 + i) * 17 + og] = ps;
    }
    __syncthreads();
    if (tid < 64) {
        float ssum = 0.f;
#pragma unroll
        for (int o = 0; o < 16; ++o) ssum += red[tid * 17 + o];
        smean[tid] = ssum * (1.0f / 128.0f);
    }
    __syncthreads();
    float mn[4];
#pragma unroll
    for (int i = 0; i < 4; ++i) mn[i] = smean[pg * 4 + i];
#pragma unroll
    for (int i = 0; i < 4; ++i) {
        float ps = 0.f;
#pragma unroll
        for (int j = 0; j < 8; ++j) {
            const float d = acc[j][i] - mn[i];
            ps += d * d;
        }
        red[(pg * 4 + i) * 17 + og] = ps;
    }
    __syncthreads();
    if (tid < 64) {
        float ssum = 0.f;
#pragma unroll
        for (int o = 0; o < 16; ++o) ssum += red[tid * 17 + o];
        srstd[tid] = 1.0f / sqrtf(ssum * (1.0f / 128.0f) + 1e-5f);
    }
    __syncthreads();
    float rs[4];
#pragma unroll
    for (int i = 0; i < 4; ++i) rs[i] = srstd[pg * 4 + i];
#pragma unroll
    for (int j = 0; j < 8; ++j) {
        const float gg = g[og * 8 + j];
        float4 o4;
        o4.x = (acc[j][0] - mn[0]) * rs[0] * gg;
        o4.y = (acc[j][1] - mn[1]) * rs[1] * gg;
        o4.z = (acc[j][2] - mn[2]) * rs[2] * gg;
        o4.w = (acc[j][3] - mn[3]) * rs[3] * gg;
        *(float4*)(out + ((size_t)b * 128 + og * 8 + j) * 16384 + p0 + pg * 4) = o4;
    }
}

extern "C" void kernel_launch(void* const* d_in, const int* in_sizes, int n_in,
                              void* d_out, int out_size, void* d_ws, size_t ws_size,
                              hipStream_t stream) {
    const float* x    = (const float*)d_in[0];
    const float* Wqkv = (const float*)d_in[1];
    const float* Wout = (const float*)d_in[2];
    const float* bout = (const float*)d_in[3];
    const float* g    = (const float*)d_in[4];
    float* out = (float*)d_out;

    float* Spart = (float*)d_ws;                              // 32*64*4*32*32 floats
    float* Zpart = Spart + (size_t)32 * NCHUNK * 4 * 32 * 32; // 32*64*128 floats
    float* ctx   = Zpart + (size_t)32 * NCHUNK * 4 * 32;      // 32*4*32*32 floats
    ushort* Wqh  = (ushort*)(ctx + (size_t)32 * 4 * 32 * 32); // 384*128 bf16 hi
    ushort* Wql  = Wqh + 384 * 128;                           // 384*128 bf16 lo
    (void)in_sizes; (void)n_in; (void)out_size; (void)ws_size;

    wsplit<<<dim3(48), 256, 0, stream>>>(Wqkv, Wqh, Wql, 384 * 128);
    la_k1<<<dim3(NCHUNK, 32), 256, 0, stream>>>(x, Wqh, Wql, Spart, Zpart);
    la_k1_reduce<<<dim3(128), 256, 0, stream>>>(Spart, Zpart, ctx);
    la_k2<<<dim3(256, 32), 256, 0, stream>>>(x, Wqkv, Wout, bout, g, ctx, out);
}

// Round 5
// 951.909 us; speedup vs baseline: 1.5673x; 1.2850x over previous
//
#include <hip/hip_runtime.h>
#include <math.h>

// LinearAttention: b=32, c=128, h=w=128 (n=16384), heads=4, dim_head=32.
// All GEMM-shaped work on split-bf16 MFMA (3-term: AhBh+AhBl+AlBh, fp32 acc).
//   wsplit: Wqkv and Wout -> bf16 hi/lo in ws.
//   K1:  k/v GEMM + S-accum on MFMA (unchanged from round 4).
//   K1b: ctx reduce; emits ctxT[b][h][e][d] packed u32(bf16h | bf16l<<16).
//   K2:  q GEMM (MFMA) -> softmax (VALU) -> out-einsum (MFMA, K=32/head)
//        -> Wout GEMM (MFMA) -> LayerNorm on fragments -> store.

#define TP 64
#define NCHUNK 64

typedef __attribute__((ext_vector_type(8))) short short8;
typedef __attribute__((ext_vector_type(4))) float f32x4;

__device__ __forceinline__ uint bf16r(float f) {
    uint u = __float_as_uint(f);
    return (u + 0x7FFFu + ((u >> 16) & 1u)) >> 16;   // RNE to bf16
}
__device__ __forceinline__ float bf16f(uint h) { return __uint_as_float(h << 16); }
__device__ __forceinline__ uint2 bsplit(float f) {
    uint h = bf16r(f);
    float r = f - bf16f(h);
    return make_uint2(h, bf16r(r));
}
__device__ __forceinline__ uint bpack(float f) {
    uint2 s = bsplit(f);
    return s.x | (s.y << 16);
}
// 8 packed u32 (lo16=h, hi16=l) -> bf16x8 of h / l halves
__device__ __forceinline__ short8 lo8(uint4 a, uint4 b) {
    uint4 r;
    r.x = (a.x & 0xFFFFu) | (a.y << 16);
    r.y = (a.z & 0xFFFFu) | (a.w << 16);
    r.z = (b.x & 0xFFFFu) | (b.y << 16);
    r.w = (b.z & 0xFFFFu) | (b.w << 16);
    return __builtin_bit_cast(short8, r);
}
__device__ __forceinline__ short8 hi8(uint4 a, uint4 b) {
    uint4 r;
    r.x = (a.x >> 16) | (a.y & 0xFFFF0000u);
    r.y = (a.z >> 16) | (a.w & 0xFFFF0000u);
    r.z = (b.x >> 16) | (b.y & 0xFFFF0000u);
    r.w = (b.z >> 16) | (b.w & 0xFFFF0000u);
    return __builtin_bit_cast(short8, r);
}

__global__ __launch_bounds__(256)
void wsplit(const float* __restrict__ W, ushort* __restrict__ Wh,
            ushort* __restrict__ Wl, int n)
{
    const int base = (blockIdx.x * 256 + threadIdx.x) * 4;
    if (base + 3 < n) {
        const float4 f = *(const float4*)(W + base);
        const uint2 a = bsplit(f.x), b2 = bsplit(f.y), c = bsplit(f.z), d = bsplit(f.w);
        ushort4 hh; hh.x = (ushort)a.x; hh.y = (ushort)b2.x; hh.z = (ushort)c.x; hh.w = (ushort)d.x;
        ushort4 ll; ll.x = (ushort)a.y; ll.y = (ushort)b2.y; ll.z = (ushort)c.y; ll.w = (ushort)d.y;
        *(ushort4*)(Wh + base) = hh;
        *(ushort4*)(Wl + base) = ll;
    }
}

#define MFMA(A, B, C) __builtin_amdgcn_mfma_f32_16x16x32_bf16((A), (B), (C), 0, 0, 0)

__global__ __launch_bounds__(256, 2)
void la_k1(const float* __restrict__ x,
           const ushort* __restrict__ Wh, const ushort* __restrict__ Wl,
           float* __restrict__ Spart, float* __restrict__ Zpart)
{
    // bytes [0,16384):      xTh bf16 [64p][128c], byte = (p*256 + 2c) ^ ((p&7)<<4)
    // bytes [16384,32768):  xTl
    // bytes [0,32768):      ekp u32 [128r][64p], byte = (r*256 + 4p) ^ ((r&7)<<4)
    // bytes [32768,65536):  vbp u32 [128r][64p]
    __shared__ __align__(16) char smb[65536];

    const int tid = threadIdx.x;
    const int b = blockIdx.y, chunk = blockIdx.x;
    const int w = tid >> 6, l = tid & 63;
    const int l15 = l & 15, lg = l >> 4;
    const int ch2 = w >> 1;        // col half (p 32*ch2..)
    const int rp  = w & 1;         // row-tile parity

    f32x4 s2[2][2];
#pragma unroll
    for (int i = 0; i < 2; ++i)
#pragma unroll
        for (int j = 0; j < 2; ++j) s2[i][j] = (f32x4){0.f, 0.f, 0.f, 0.f};
    float zacc = 0.f;

    float ka[8][4], va[8][4];

    for (int t = 0; t < 4; ++t) {
        const int p0 = (chunk * 4 + t) * TP;
        const float* xb = x + (size_t)b * 128 * 16384 + p0;

        // ---- stage x -> xTh/xTl (in-register 4x4 transpose) ----
        {
            const int j = tid & 15, g = tid >> 4;
            const int pb = j * 4;
#pragma unroll
            for (int u = 0; u < 2; ++u) {
                const int cb = g * 4 + u * 64;
                const float4 xv0 = *(const float4*)(xb + (size_t)(cb + 0) * 16384 + pb);
                const float4 xv1 = *(const float4*)(xb + (size_t)(cb + 1) * 16384 + pb);
                const float4 xv2 = *(const float4*)(xb + (size_t)(cb + 2) * 16384 + pb);
                const float4 xv3 = *(const float4*)(xb + (size_t)(cb + 3) * 16384 + pb);
                float rc[4][4];
                rc[0][0] = xv0.x; rc[0][1] = xv0.y; rc[0][2] = xv0.z; rc[0][3] = xv0.w;
                rc[1][0] = xv1.x; rc[1][1] = xv1.y; rc[1][2] = xv1.z; rc[1][3] = xv1.w;
                rc[2][0] = xv2.x; rc[2][1] = xv2.y; rc[2][2] = xv2.z; rc[2][3] = xv2.w;
                rc[3][0] = xv3.x; rc[3][1] = xv3.y; rc[3][2] = xv3.z; rc[3][3] = xv3.w;
#pragma unroll
                for (int pp = 0; pp < 4; ++pp) {
                    const uint2 s0 = bsplit(rc[0][pp]);
                    const uint2 s1 = bsplit(rc[1][pp]);
                    const uint2 s2u = bsplit(rc[2][pp]);
                    const uint2 s3 = bsplit(rc[3][pp]);
                    const int p = pb + pp;
                    const int byt = (p * 256 + cb * 2) ^ ((p & 7) << 4);
                    *(uint2*)(&smb[byt])         = make_uint2(s0.x | (s1.x << 16), s2u.x | (s3.x << 16));
                    *(uint2*)(&smb[16384 + byt]) = make_uint2(s0.y | (s1.y << 16), s2u.y | (s3.y << 16));
                }
            }
        }
        __syncthreads();

        // ---- k/v GEMM: C[256 rows][64 p] via split-bf16 MFMA ----
        f32x4 acc[8][2];
#pragma unroll
        for (int rt = 0; rt < 8; ++rt)
#pragma unroll
            for (int ct = 0; ct < 2; ++ct) acc[rt][ct] = (f32x4){0.f, 0.f, 0.f, 0.f};

#pragma unroll
        for (int ks = 0; ks < 4; ++ks) {
            short8 Bh[2], Bl[2];
#pragma unroll
            for (int ct = 0; ct < 2; ++ct) {
                const int p = ch2 * 32 + ct * 16 + l15;
                const int byt = (p * 256 + (ks * 32 + lg * 8) * 2) ^ ((p & 7) << 4);
                Bh[ct] = *(const short8*)(&smb[byt]);
                Bl[ct] = *(const short8*)(&smb[16384 + byt]);
            }
#pragma unroll
            for (int rt = 0; rt < 8; ++rt) {
                const int T = rt * 2 + rp;                  // global row-tile 0..15
                const size_t aoff = (size_t)(128 + T * 16 + l15) * 128 + ks * 32 + lg * 8;
                const short8 Ah_ = *(const short8*)(Wh + aoff);
                const short8 Al_ = *(const short8*)(Wl + aoff);
#pragma unroll
                for (int ct = 0; ct < 2; ++ct) {
                    acc[rt][ct] = MFMA(Ah_, Bh[ct], acc[rt][ct]);
                    acc[rt][ct] = MFMA(Ah_, Bl[ct], acc[rt][ct]);
                    acc[rt][ct] = MFMA(Al_, Bh[ct], acc[rt][ct]);
                }
            }
        }
        __syncthreads();   // all xT reads done; ek may overwrite

        // ---- producer: exp(k)/v -> packed u32 rows ----
#pragma unroll
        for (int rt = 0; rt < 8; ++rt) {
            const int T = rt * 2 + rp;
            const bool isk = (T < 8);
            const int rbase = (T & 7) * 16 + lg * 4;
#pragma unroll
            for (int ct = 0; ct < 2; ++ct) {
                const int p = ch2 * 32 + ct * 16 + l15;
#pragma unroll
                for (int i = 0; i < 4; ++i) {
                    float val = acc[rt][ct][i];
                    if (isk) val = expf(val);
                    const int r = rbase + i;
                    const uint2 hl = bsplit(val);
                    const int byt = (r * 256 + p * 4) ^ ((r & 7) << 4);
                    *(uint*)(&smb[(isk ? 0 : 32768) + byt]) = hl.x | (hl.y << 16);
                }
            }
        }
        __syncthreads();

        // ---- S-phase MFMA: head w, S[32d][32e] += ek * v^T over 64 p ----
#pragma unroll
        for (int ks2 = 0; ks2 < 2; ++ks2) {
            const int pq = ks2 * 32 + lg * 8;
            short8 A2h[2], A2l[2], B2h[2], B2l[2];
#pragma unroll
            for (int rt2 = 0; rt2 < 2; ++rt2) {
                const int r = w * 32 + rt2 * 16 + l15;
                const int b0 = (r * 256 + pq * 4) ^ ((r & 7) << 4);
                const int b1 = (r * 256 + pq * 4 + 16) ^ ((r & 7) << 4);
                const uint4 q0 = *(const uint4*)(&smb[b0]);
                const uint4 q1 = *(const uint4*)(&smb[b1]);
                A2h[rt2] = lo8(q0, q1);
                A2l[rt2] = hi8(q0, q1);
                const uint4 r0 = *(const uint4*)(&smb[32768 + b0]);
                const uint4 r1 = *(const uint4*)(&smb[32768 + b1]);
                B2h[rt2] = lo8(r0, r1);
                B2l[rt2] = hi8(r0, r1);
            }
#pragma unroll
            for (int rt2 = 0; rt2 < 2; ++rt2)
#pragma unroll
                for (int ct2 = 0; ct2 < 2; ++ct2) {
                    s2[rt2][ct2] = MFMA(A2h[rt2], B2h[ct2], s2[rt2][ct2]);
                    s2[rt2][ct2] = MFMA(A2h[rt2], B2l[ct2], s2[rt2][ct2]);
                    s2[rt2][ct2] = MFMA(A2l[rt2], B2h[ct2], s2[rt2][ct2]);
                }
        }
        // ---- Z: per-row sum of exp(k) (h+l reconstruct) ----
        {
            const int r = tid >> 1;
            const int ph = (tid & 1) * 32;
            float zs = 0.f;
#pragma unroll
            for (int c = 0; c < 8; ++c) {
                const int byt = (r * 256 + (ph + c * 4) * 4) ^ ((r & 7) << 4);
                const uint4 q = *(const uint4*)(&smb[byt]);
                zs += bf16f(q.x & 0xFFFFu) + bf16f(q.x >> 16)
                    + bf16f(q.y & 0xFFFFu) + bf16f(q.y >> 16)
                    + bf16f(q.z & 0xFFFFu) + bf16f(q.z >> 16)
                    + bf16f(q.w & 0xFFFFu) + bf16f(q.w >> 16);
            }
            zacc += zs;
        }
        __syncthreads();   // ek/vb consumed; next tile may restage
    }

    // ---- write S partials: Spart[b][ch][head=w][d][e] ----
    const size_t sbase = (((size_t)b * NCHUNK + chunk) * 4 + w) * 1024;
#pragma unroll
    for (int rt2 = 0; rt2 < 2; ++rt2)
#pragma unroll
        for (int ct2 = 0; ct2 < 2; ++ct2)
#pragma unroll
            for (int i = 0; i < 4; ++i) {
                const int d = rt2 * 16 + lg * 4 + i;
                const int e = ct2 * 16 + l15;
                Spart[sbase + d * 32 + e] = s2[rt2][ct2][i];
            }
    // ---- Z: pair-reduce and write ----
    const float ztot = zacc + __shfl_xor(zacc, 1, 64);
    if ((tid & 1) == 0)
        Zpart[((size_t)b * NCHUNK + chunk) * 128 + (tid >> 1)] = ztot;
}

__global__ __launch_bounds__(256, 1)
void la_k1_reduce(const float* __restrict__ Spart, const float* __restrict__ Zpart,
                  uint* __restrict__ ctxT)
{
    const int tid = threadIdx.x;
    const int b  = blockIdx.x >> 2;
    const int hh = blockIdx.x & 3;
    const int d  = tid >> 3;
    const int e0 = (tid & 7) << 2;
    float sx = 0.f, sy = 0.f, sz = 0.f, sw = 0.f, z = 0.f;
    for (int ch = 0; ch < NCHUNK; ++ch) {
        const size_t base = (((size_t)b * NCHUNK + ch) * 4 + hh) * 32 + d;
        const float4 v = *(const float4*)(Spart + base * 32 + e0);
        sx += v.x; sy += v.y; sz += v.z; sw += v.w;
        z += Zpart[base];
    }
    const float inv = 1.0f / (z * 16384.0f);
    // ctxT[b][h][e][d] packed bf16 h/l
    const size_t tb = (((size_t)b * 4 + hh) * 32) * 32 + d;
    ctxT[tb + (size_t)(e0 + 0) * 32] = bpack(sx * inv);
    ctxT[tb + (size_t)(e0 + 1) * 32] = bpack(sy * inv);
    ctxT[tb + (size_t)(e0 + 2) * 32] = bpack(sz * inv);
    ctxT[tb + (size_t)(e0 + 3) * 32] = bpack(sw * inv);
}

// K2: q GEMM -> softmax -> out-einsum -> Wout GEMM -> LayerNorm, all fused.
// LDS regions:
//   R0 [0,32768):     xTh/xTl  ->  q fp32 [128r][64p] swz  ->  out u32 [64p][128e] swz
//   R1 [32768,65536):  qsT u32 [4sh][64p][32d], byte = (base+ofs)^(((p>>2)&7)<<4)
//   R2 [65536,66560):  lnred [64p][2rp][2]
__global__ __launch_bounds__(256, 2)
void la_k2(const float* __restrict__ x,
           const ushort* __restrict__ Wqh, const ushort* __restrict__ Wql,
           const ushort* __restrict__ Woh, const ushort* __restrict__ Wol,
           const float* __restrict__ bout, const float* __restrict__ g,
           const uint* __restrict__ ctxT, float* __restrict__ outg)
{
    __shared__ __align__(16) char smb[66560];

    const int tid = threadIdx.x;
    const int b = blockIdx.y, chunk = blockIdx.x;
    const int p0 = chunk * TP;
    const int w = tid >> 6, l = tid & 63;
    const int l15 = l & 15, lg = l >> 4;
    const int ch2 = w >> 1;        // col half
    const int rp  = w & 1;         // row-tile parity

    // ---- phase 1: stage x -> xTh/xTl ----
    {
        const float* xb = x + (size_t)b * 128 * 16384 + p0;
        const int j = tid & 15, gq = tid >> 4;
        const int pb = j * 4;
#pragma unroll
        for (int u = 0; u < 2; ++u) {
            const int cb = gq * 4 + u * 64;
            const float4 xv0 = *(const float4*)(xb + (size_t)(cb + 0) * 16384 + pb);
            const float4 xv1 = *(const float4*)(xb + (size_t)(cb + 1) * 16384 + pb);
            const float4 xv2 = *(const float4*)(xb + (size_t)(cb + 2) * 16384 + pb);
            const float4 xv3 = *(const float4*)(xb + (size_t)(cb + 3) * 16384 + pb);
            float rc[4][4];
            rc[0][0] = xv0.x; rc[0][1] = xv0.y; rc[0][2] = xv0.z; rc[0][3] = xv0.w;
            rc[1][0] = xv1.x; rc[1][1] = xv1.y; rc[1][2] = xv1.z; rc[1][3] = xv1.w;
            rc[2][0] = xv2.x; rc[2][1] = xv2.y; rc[2][2] = xv2.z; rc[2][3] = xv2.w;
            rc[3][0] = xv3.x; rc[3][1] = xv3.y; rc[3][2] = xv3.z; rc[3][3] = xv3.w;
#pragma unroll
            for (int pp = 0; pp < 4; ++pp) {
                const uint2 s0 = bsplit(rc[0][pp]);
                const uint2 s1 = bsplit(rc[1][pp]);
                const uint2 s2u = bsplit(rc[2][pp]);
                const uint2 s3 = bsplit(rc[3][pp]);
                const int p = pb + pp;
                const int byt = (p * 256 + cb * 2) ^ ((p & 7) << 4);
                *(uint2*)(&smb[byt])         = make_uint2(s0.x | (s1.x << 16), s2u.x | (s3.x << 16));
                *(uint2*)(&smb[16384 + byt]) = make_uint2(s0.y | (s1.y << 16), s2u.y | (s3.y << 16));
            }
        }
    }
    __syncthreads();

    // ---- phase 2: q GEMM (Wqkv rows 0..127): C[128 q-rows][64 p] ----
    f32x4 qacc[4][2];
#pragma unroll
    for (int j = 0; j < 4; ++j)
#pragma unroll
        for (int ct = 0; ct < 2; ++ct) qacc[j][ct] = (f32x4){0.f, 0.f, 0.f, 0.f};
#pragma unroll
    for (int ks = 0; ks < 4; ++ks) {
        short8 Bh[2], Bl[2];
#pragma unroll
        for (int ct = 0; ct < 2; ++ct) {
            const int p = ch2 * 32 + ct * 16 + l15;
            const int byt = (p * 256 + (ks * 32 + lg * 8) * 2) ^ ((p & 7) << 4);
            Bh[ct] = *(const short8*)(&smb[byt]);
            Bl[ct] = *(const short8*)(&smb[16384 + byt]);
        }
#pragma unroll
        for (int j = 0; j < 4; ++j) {
            const int T = rp + 2 * j;                  // row-tile 0..7
            const size_t aoff = (size_t)(T * 16 + l15) * 128 + ks * 32 + lg * 8;
            const short8 Ah_ = *(const short8*)(Wqh + aoff);
            const short8 Al_ = *(const short8*)(Wql + aoff);
#pragma unroll
            for (int ct = 0; ct < 2; ++ct) {
                qacc[j][ct] = MFMA(Ah_, Bh[ct], qacc[j][ct]);
                qacc[j][ct] = MFMA(Ah_, Bl[ct], qacc[j][ct]);
                qacc[j][ct] = MFMA(Al_, Bh[ct], qacc[j][ct]);
            }
        }
    }
    __syncthreads();   // xT reads done

    // ---- phase 3: write q fp32 to R0, [row][64p], p ^= ((row>>2)&1)<<4 ----
    {
        float* qsf = (float*)smb;
#pragma unroll
        for (int j = 0; j < 4; ++j) {
            const int T = rp + 2 * j;
#pragma unroll
            for (int ct = 0; ct < 2; ++ct) {
                const int p = ch2 * 32 + ct * 16 + l15;
#pragma unroll
                for (int i = 0; i < 4; ++i) {
                    const int row = T * 16 + lg * 4 + i;
                    qsf[row * 64 + (p ^ (((row >> 2) & 1) << 4))] = qacc[j][ct][i];
                }
            }
        }
    }
    __syncthreads();

    // ---- phase 4: softmax over d per (p, head), *scale; pack to qsT ----
    {
        const float* qsf = (const float*)smb;
        const int p  = tid & 63;
        const int sh = tid >> 6;
        float v[32];
        float m = -1e30f;
#pragma unroll
        for (int d = 0; d < 32; ++d) {
            const int row = sh * 32 + d;
            v[d] = qsf[row * 64 + (p ^ (((d >> 2) & 1) << 4))];
            m = fmaxf(m, v[d]);
        }
        float s = 0.f;
#pragma unroll
        for (int d = 0; d < 32; ++d) { v[d] = expf(v[d] - m); s += v[d]; }
        const float inv = 0.17677669529663687f / s;   // 32^-0.5 / s
        const int base = (sh * 64 + p) * 128;
        const int swz = ((p >> 2) & 7) << 4;
#pragma unroll
        for (int db = 0; db < 8; ++db) {
            uint4 pk;
            pk.x = bpack(v[db * 4 + 0] * inv);
            pk.y = bpack(v[db * 4 + 1] * inv);
            pk.z = bpack(v[db * 4 + 2] * inv);
            pk.w = bpack(v[db * 4 + 3] * inv);
            *(uint4*)(&smb[32768 + ((base + db * 16) ^ swz)]) = pk;
        }
    }
    __syncthreads();

    // ---- phase 5: out-einsum: out[e][p] = ctx^T q_s (K=32 per head) ----
    {
#pragma unroll
        for (int j = 0; j < 4; ++j) {
            const int rt = rp + 2 * j;
            const int sh = rt >> 1;          // head
            const int et = rt & 1;           // e-half within head
            // A-frag: ctxT[b][sh][e][d], row e = et*16+l15, k = lg*8..
            const size_t aidx = ((((size_t)b * 4 + sh) * 32) + et * 16 + l15) * 32 + lg * 8;
            const uint4 a0 = *(const uint4*)(ctxT + aidx);
            const uint4 a1 = *(const uint4*)(ctxT + aidx + 4);
            const short8 Ah_ = lo8(a0, a1);
            const short8 Al_ = hi8(a0, a1);
            f32x4 oacc[2];
#pragma unroll
            for (int ct = 0; ct < 2; ++ct) {
                oacc[ct] = (f32x4){0.f, 0.f, 0.f, 0.f};
                const int p = ch2 * 32 + ct * 16 + l15;
                const int bb = (sh * 64 + p) * 128;
                const int swz = ((p >> 2) & 7) << 4;
                const uint4 r0 = *(const uint4*)(&smb[32768 + ((bb + lg * 32) ^ swz)]);
                const uint4 r1 = *(const uint4*)(&smb[32768 + ((bb + lg * 32 + 16) ^ swz)]);
                const short8 Bh_ = lo8(r0, r1);
                const short8 Bl_ = hi8(r0, r1);
                oacc[ct] = MFMA(Ah_, Bh_, oacc[ct]);
                oacc[ct] = MFMA(Ah_, Bl_, oacc[ct]);
                oacc[ct] = MFMA(Al_, Bh_, oacc[ct]);
            }
            // write out u32 [p][e]: byte = (p*512 + e*4) ^ ((p&7)<<4)
#pragma unroll
            for (int ct = 0; ct < 2; ++ct) {
                const int p = ch2 * 32 + ct * 16 + l15;
#pragma unroll
                for (int i = 0; i < 4; ++i) {
                    const int eg = rt * 16 + lg * 4 + i;
                    *(uint*)(&smb[(p * 512 + eg * 4) ^ ((p & 7) << 4)]) = bpack(oacc[ct][i]);
                }
            }
        }
    }
    __syncthreads();

    // ---- phase 6: y = Wout * out + bout ----
    f32x4 yacc[4][2];
#pragma unroll
    for (int j = 0; j < 4; ++j)
#pragma unroll
        for (int ct = 0; ct < 2; ++ct) yacc[j][ct] = (f32x4){0.f, 0.f, 0.f, 0.f};
#pragma unroll
    for (int ks = 0; ks < 4; ++ks) {
        short8 Bh[2], Bl[2];
#pragma unroll
        for (int ct = 0; ct < 2; ++ct) {
            const int p = ch2 * 32 + ct * 16 + l15;
            const int bb = p * 512 + (ks * 32 + lg * 8) * 4;
            const int swz = (p & 7) << 4;
            const uint4 r0 = *(const uint4*)(&smb[(bb) ^ swz]);
            const uint4 r1 = *(const uint4*)(&smb[(bb + 16) ^ swz]);
            Bh[ct] = lo8(r0, r1);
            Bl[ct] = hi8(r0, r1);
        }
#pragma unroll
        for (int j = 0; j < 4; ++j) {
            const int T = rp + 2 * j;
            const size_t aoff = (size_t)(T * 16 + l15) * 128 + ks * 32 + lg * 8;
            const short8 Ah_ = *(const short8*)(Woh + aoff);
            const short8 Al_ = *(const short8*)(Wol + aoff);
#pragma unroll
            for (int ct = 0; ct < 2; ++ct) {
                yacc[j][ct] = MFMA(Ah_, Bh[ct], yacc[j][ct]);
                yacc[j][ct] = MFMA(Ah_, Bl[ct], yacc[j][ct]);
                yacc[j][ct] = MFMA(Al_, Bh[ct], yacc[j][ct]);
            }
        }
    }

    // ---- phase 7: + bout, LayerNorm over 128 channels, * g, store ----
    float4 bo[4], gv[4];
#pragma unroll
    for (int j = 0; j < 4; ++j) {
        const int rbase = (rp + 2 * j) * 16 + lg * 4;
        bo[j] = *(const float4*)(bout + rbase);
        gv[j] = *(const float4*)(g + rbase);
    }
#pragma unroll
    for (int j = 0; j < 4; ++j)
#pragma unroll
        for (int ct = 0; ct < 2; ++ct) {
            yacc[j][ct][0] += bo[j].x;
            yacc[j][ct][1] += bo[j].y;
            yacc[j][ct][2] += bo[j].z;
            yacc[j][ct][3] += bo[j].w;
        }
    // per-ct: sum & sumsq over this lane's 16 rows, then over lg via shfl
    float* lnred = (float*)(smb + 65536);   // [64p][2rp][2]
    float sm[2], sq[2];
#pragma unroll
    for (int ct = 0; ct < 2; ++ct) {
        float s = 0.f, q = 0.f;
#pragma unroll
        for (int j = 0; j < 4; ++j)
#pragma unroll
            for (int i = 0; i < 4; ++i) {
                const float yv = yacc[j][ct][i];
                s += yv; q += yv * yv;
            }
        s += __shfl_xor(s, 16, 64); q += __shfl_xor(q, 16, 64);
        s += __shfl_xor(s, 32, 64); q += __shfl_xor(q, 32, 64);
        sm[ct] = s; sq[ct] = q;
    }
    if (lg == 0) {
#pragma unroll
        for (int ct = 0; ct < 2; ++ct) {
            const int p = ch2 * 32 + ct * 16 + l15;
            lnred[(p * 2 + rp) * 2 + 0] = sm[ct];
            lnred[(p * 2 + rp) * 2 + 1] = sq[ct];
        }
    }
    __syncthreads();
#pragma unroll
    for (int ct = 0; ct < 2; ++ct) {
        const int p = ch2 * 32 + ct * 16 + l15;
        const float st = lnred[(p * 2 + 0) * 2 + 0] + lnred[(p * 2 + 1) * 2 + 0];
        const float qt = lnred[(p * 2 + 0) * 2 + 1] + lnred[(p * 2 + 1) * 2 + 1];
        const float mean = st * (1.0f / 128.0f);
        const float var  = qt * (1.0f / 128.0f) - mean * mean;
        const float rstd = 1.0f / sqrtf(var + 1e-5f);
#pragma unroll
        for (int j = 0; j < 4; ++j) {
            const int rbase = (rp + 2 * j) * 16 + lg * 4;
            const float gg[4] = {gv[j].x, gv[j].y, gv[j].z, gv[j].w};
#pragma unroll
            for (int i = 0; i < 4; ++i) {
                const float val = (yacc[j][ct][i] - mean) * rstd * gg[i];
                outg[((size_t)b * 128 + rbase + i) * 16384 + p0 + p] = val;
            }
        }
    }
}

extern "C" void kernel_launch(void* const* d_in, const int* in_sizes, int n_in,
                              void* d_out, int out_size, void* d_ws, size_t ws_size,
                              hipStream_t stream) {
    const float* x    = (const float*)d_in[0];
    const float* Wqkv = (const float*)d_in[1];
    const float* Wout = (const float*)d_in[2];
    const float* bout = (const float*)d_in[3];
    const float* g    = (const float*)d_in[4];
    float* out = (float*)d_out;

    float* Spart = (float*)d_ws;                              // 32*64*4*32*32 floats
    float* Zpart = Spart + (size_t)32 * NCHUNK * 4 * 32 * 32; // 32*64*128 floats
    uint*  ctxT  = (uint*)(Zpart + (size_t)32 * NCHUNK * 4 * 32); // 32*4*32*32 u32
    ushort* Wqh  = (ushort*)(ctxT + (size_t)32 * 4 * 32 * 32);    // 384*128
    ushort* Wql  = Wqh + 384 * 128;
    ushort* Woh  = Wql + 384 * 128;                               // 128*128
    ushort* Wol  = Woh + 128 * 128;
    (void)in_sizes; (void)n_in; (void)out_size; (void)ws_size;

    wsplit<<<dim3(48), 256, 0, stream>>>(Wqkv, Wqh, Wql, 384 * 128);
    wsplit<<<dim3(16), 256, 0, stream>>>(Wout, Woh, Wol, 128 * 128);
    la_k1<<<dim3(NCHUNK, 32), 256, 0, stream>>>(x, Wqh, Wql, Spart, Zpart);
    la_k1_reduce<<<dim3(128), 256, 0, stream>>>(Spart, Zpart, ctxT);
    la_k2<<<dim3(256, 32), 256, 0, stream>>>(x, Wqh, Wql, Woh, Wol, bout, g, ctxT, out);
}

// Round 6
// 704.602 us; speedup vs baseline: 2.1174x; 1.3510x over previous
//
#include <hip/hip_runtime.h>
#include <math.h>

// LinearAttention: b=32, c=128, h=w=128 (n=16384), heads=4, dim_head=32.
// All GEMM-shaped work on split-bf16 MFMA (3-term: AhBh+AhBl+AlBh, fp32 acc).
//   wsplit: Wqkv and Wout -> bf16 hi/lo in ws.
//   K1:  W A-fragments hoisted to registers (once/block); k/v GEMM + S-accum
//        on MFMA; Z in registers via shfl butterfly; xT swizzle (p^(p>>3))&7.
//   K1b: ctx reduce; emits ctxT[b][h][e][d] packed u32(bf16h | bf16l<<16).
//   K2:  q GEMM -> softmax -> out-einsum -> Wout GEMM -> LayerNorm (unchanged).

#define TP 64
#define NCHUNK 64

typedef __attribute__((ext_vector_type(8))) short short8;
typedef __attribute__((ext_vector_type(4))) float f32x4;

__device__ __forceinline__ uint bf16r(float f) {
    uint u = __float_as_uint(f);
    return (u + 0x7FFFu + ((u >> 16) & 1u)) >> 16;   // RNE to bf16
}
__device__ __forceinline__ float bf16f(uint h) { return __uint_as_float(h << 16); }
__device__ __forceinline__ uint2 bsplit(float f) {
    uint h = bf16r(f);
    float r = f - bf16f(h);
    return make_uint2(h, bf16r(r));
}
__device__ __forceinline__ uint bpack(float f) {
    uint2 s = bsplit(f);
    return s.x | (s.y << 16);
}
__device__ __forceinline__ short8 lo8(uint4 a, uint4 b) {
    uint4 r;
    r.x = (a.x & 0xFFFFu) | (a.y << 16);
    r.y = (a.z & 0xFFFFu) | (a.w << 16);
    r.z = (b.x & 0xFFFFu) | (b.y << 16);
    r.w = (b.z & 0xFFFFu) | (b.w << 16);
    return __builtin_bit_cast(short8, r);
}
__device__ __forceinline__ short8 hi8(uint4 a, uint4 b) {
    uint4 r;
    r.x = (a.x >> 16) | (a.y & 0xFFFF0000u);
    r.y = (a.z >> 16) | (a.w & 0xFFFF0000u);
    r.z = (b.x >> 16) | (b.y & 0xFFFF0000u);
    r.w = (b.z >> 16) | (b.w & 0xFFFF0000u);
    return __builtin_bit_cast(short8, r);
}

// xT layout: byte = p*256 + 2c, XOR quad-swizzle with ((p ^ (p>>3)) & 7)<<4.
// Conflict-free for both stage stores (p via j spreads all 8 quads) and
// GEMM B-reads (l15-consecutive p spreads all 8 quads per octet).
__device__ __forceinline__ int xswz(int p, int cbyte) {
    return (p * 256 + cbyte) ^ (((p ^ (p >> 3)) & 7) << 4);
}

__global__ __launch_bounds__(256)
void wsplit(const float* __restrict__ W, ushort* __restrict__ Wh,
            ushort* __restrict__ Wl, int n)
{
    const int base = (blockIdx.x * 256 + threadIdx.x) * 4;
    if (base + 3 < n) {
        const float4 f = *(const float4*)(W + base);
        const uint2 a = bsplit(f.x), b2 = bsplit(f.y), c = bsplit(f.z), d = bsplit(f.w);
        ushort4 hh; hh.x = (ushort)a.x; hh.y = (ushort)b2.x; hh.z = (ushort)c.x; hh.w = (ushort)d.x;
        ushort4 ll; ll.x = (ushort)a.y; ll.y = (ushort)b2.y; ll.z = (ushort)c.y; ll.w = (ushort)d.y;
        *(ushort4*)(Wh + base) = hh;
        *(ushort4*)(Wl + base) = ll;
    }
}

#define MFMA(A, B, C) __builtin_amdgcn_mfma_f32_16x16x32_bf16((A), (B), (C), 0, 0, 0)

__global__ __launch_bounds__(256, 2)
void la_k1(const float* __restrict__ x,
           const ushort* __restrict__ Wh, const ushort* __restrict__ Wl,
           float* __restrict__ Spart, float* __restrict__ Zpart)
{
    // bytes [0,16384):      xTh bf16 [64p][128c], xswz
    // bytes [16384,32768):  xTl
    // bytes [0,32768):      ekp u32 [128r][64p], byte = (r*256 + 4p) ^ ((r&7)<<4)
    // bytes [32768,65536):  vbp u32 [128r][64p]
    __shared__ __align__(16) char smb[65536];

    const int tid = threadIdx.x;
    const int b = blockIdx.y, chunk = blockIdx.x;
    const int w = tid >> 6, l = tid & 63;
    const int l15 = l & 15, lg = l >> 4;

    // ---- prologue: hoist A-fragments. wave w owns row-tiles T = rt*4 + w ----
    short8 Ah[4][4], Al[4][4];
#pragma unroll
    for (int rt = 0; rt < 4; ++rt) {
        const int T = rt * 4 + w;
#pragma unroll
        for (int ks = 0; ks < 4; ++ks) {
            const size_t aoff = (size_t)(128 + T * 16 + l15) * 128 + ks * 32 + lg * 8;
            Ah[rt][ks] = *(const short8*)(Wh + aoff);
            Al[rt][ks] = *(const short8*)(Wl + aoff);
        }
    }

    f32x4 s2[2][2];            // S accumulator, head = w
#pragma unroll
    for (int i = 0; i < 2; ++i)
#pragma unroll
        for (int j = 0; j < 2; ++j) s2[i][j] = (f32x4){0.f, 0.f, 0.f, 0.f};
    float zrow[2][4];          // Z partials for k-tiles rt=0,1
#pragma unroll
    for (int i = 0; i < 2; ++i)
#pragma unroll
        for (int j = 0; j < 4; ++j) zrow[i][j] = 0.f;

    for (int t = 0; t < 4; ++t) {
        const int p0 = (chunk * 4 + t) * TP;
        const float* xb = x + (size_t)b * 128 * 16384 + p0;

        // ---- stage x -> xTh/xTl (in-register 4x4 transpose) ----
        {
            const int j = tid & 15, g = tid >> 4;
            const int pb = j * 4;
#pragma unroll
            for (int u = 0; u < 2; ++u) {
                const int cb = g * 4 + u * 64;
                const float4 xv0 = *(const float4*)(xb + (size_t)(cb + 0) * 16384 + pb);
                const float4 xv1 = *(const float4*)(xb + (size_t)(cb + 1) * 16384 + pb);
                const float4 xv2 = *(const float4*)(xb + (size_t)(cb + 2) * 16384 + pb);
                const float4 xv3 = *(const float4*)(xb + (size_t)(cb + 3) * 16384 + pb);
                float rc[4][4];
                rc[0][0] = xv0.x; rc[0][1] = xv0.y; rc[0][2] = xv0.z; rc[0][3] = xv0.w;
                rc[1][0] = xv1.x; rc[1][1] = xv1.y; rc[1][2] = xv1.z; rc[1][3] = xv1.w;
                rc[2][0] = xv2.x; rc[2][1] = xv2.y; rc[2][2] = xv2.z; rc[2][3] = xv2.w;
                rc[3][0] = xv3.x; rc[3][1] = xv3.y; rc[3][2] = xv3.z; rc[3][3] = xv3.w;
#pragma unroll
                for (int pp = 0; pp < 4; ++pp) {
                    const uint2 s0 = bsplit(rc[0][pp]);
                    const uint2 s1 = bsplit(rc[1][pp]);
                    const uint2 s2u = bsplit(rc[2][pp]);
                    const uint2 s3 = bsplit(rc[3][pp]);
                    const int p = pb + pp;
                    const int byt = xswz(p, cb * 2);
                    *(uint2*)(&smb[byt])         = make_uint2(s0.x | (s1.x << 16), s2u.x | (s3.x << 16));
                    *(uint2*)(&smb[16384 + byt]) = make_uint2(s0.y | (s1.y << 16), s2u.y | (s3.y << 16));
                }
            }
        }
        __syncthreads();

        // ---- k/v GEMM: registers-A x LDS-B, pure MFMA ----
        f32x4 acc[4][4];
#pragma unroll
        for (int rt = 0; rt < 4; ++rt)
#pragma unroll
            for (int ct = 0; ct < 4; ++ct) acc[rt][ct] = (f32x4){0.f, 0.f, 0.f, 0.f};
#pragma unroll
        for (int ks = 0; ks < 4; ++ks) {
#pragma unroll
            for (int ct = 0; ct < 4; ++ct) {
                const int p = ct * 16 + l15;
                const int byt = xswz(p, (ks * 32 + lg * 8) * 2);
                const short8 Bh_ = *(const short8*)(&smb[byt]);
                const short8 Bl_ = *(const short8*)(&smb[16384 + byt]);
#pragma unroll
                for (int rt = 0; rt < 4; ++rt) {
                    acc[rt][ct] = MFMA(Ah[rt][ks], Bh_, acc[rt][ct]);
                    acc[rt][ct] = MFMA(Ah[rt][ks], Bl_, acc[rt][ct]);
                    acc[rt][ct] = MFMA(Al[rt][ks], Bh_, acc[rt][ct]);
                }
            }
        }
        __syncthreads();   // all xT reads done; ek may overwrite

        // ---- producer: exp(k)/v -> packed u32 rows; Z in registers ----
#pragma unroll
        for (int rt = 0; rt < 4; ++rt) {
            const int T = rt * 4 + w;
            const int rbase = (T & 7) * 16 + lg * 4;
#pragma unroll
            for (int ct = 0; ct < 4; ++ct) {
                const int p = ct * 16 + l15;
#pragma unroll
                for (int i = 0; i < 4; ++i) {
                    float val = acc[rt][ct][i];
                    if (rt < 2) {                       // k tile
                        val = expf(val);
                        zrow[rt & 1][i] += val;
                    }
                    const int r = rbase + i;
                    const uint2 hl = bsplit(val);
                    const int byt = (r * 256 + p * 4) ^ ((r & 7) << 4);
                    *(uint*)(&smb[(rt < 2 ? 0 : 32768) + byt]) = hl.x | (hl.y << 16);
                }
            }
        }
        __syncthreads();

        // ---- S-phase MFMA: head w, S[32d][32e] += ek * v^T over 64 p ----
#pragma unroll
        for (int ks2 = 0; ks2 < 2; ++ks2) {
            const int pq = ks2 * 32 + lg * 8;
            short8 A2h[2], A2l[2], B2h[2], B2l[2];
#pragma unroll
            for (int rt2 = 0; rt2 < 2; ++rt2) {
                const int r = w * 32 + rt2 * 16 + l15;
                const int b0 = (r * 256 + pq * 4) ^ ((r & 7) << 4);
                const int b1 = (r * 256 + pq * 4 + 16) ^ ((r & 7) << 4);
                const uint4 q0 = *(const uint4*)(&smb[b0]);
                const uint4 q1 = *(const uint4*)(&smb[b1]);
                A2h[rt2] = lo8(q0, q1);
                A2l[rt2] = hi8(q0, q1);
                const uint4 r0 = *(const uint4*)(&smb[32768 + b0]);
                const uint4 r1 = *(const uint4*)(&smb[32768 + b1]);
                B2h[rt2] = lo8(r0, r1);
                B2l[rt2] = hi8(r0, r1);
            }
#pragma unroll
            for (int rt2 = 0; rt2 < 2; ++rt2)
#pragma unroll
                for (int ct2 = 0; ct2 < 2; ++ct2) {
                    s2[rt2][ct2] = MFMA(A2h[rt2], B2h[ct2], s2[rt2][ct2]);
                    s2[rt2][ct2] = MFMA(A2h[rt2], B2l[ct2], s2[rt2][ct2]);
                    s2[rt2][ct2] = MFMA(A2l[rt2], B2h[ct2], s2[rt2][ct2]);
                }
        }
        __syncthreads();   // ek/vb consumed; next tile may restage
    }

    // ---- write S partials: Spart[b][ch][head=w][d][e] ----
    const size_t sbase = (((size_t)b * NCHUNK + chunk) * 4 + w) * 1024;
#pragma unroll
    for (int rt2 = 0; rt2 < 2; ++rt2)
#pragma unroll
        for (int ct2 = 0; ct2 < 2; ++ct2)
#pragma unroll
            for (int i = 0; i < 4; ++i) {
                const int d = rt2 * 16 + lg * 4 + i;
                const int e = ct2 * 16 + l15;
                Spart[sbase + d * 32 + e] = s2[rt2][ct2][i];
            }

    // ---- Z: butterfly-reduce over l15, write per k-row ----
#pragma unroll
    for (int rt = 0; rt < 2; ++rt)
#pragma unroll
        for (int i = 0; i < 4; ++i) {
            float z = zrow[rt][i];
            z += __shfl_xor(z, 1, 64);
            z += __shfl_xor(z, 2, 64);
            z += __shfl_xor(z, 4, 64);
            z += __shfl_xor(z, 8, 64);
            if (l15 == 0) {
                const int T = rt * 4 + w;   // k tile index 0..7
                Zpart[((size_t)b * NCHUNK + chunk) * 128 + T * 16 + lg * 4 + i] = z;
            }
        }
}

__global__ __launch_bounds__(256, 1)
void la_k1_reduce(const float* __restrict__ Spart, const float* __restrict__ Zpart,
                  uint* __restrict__ ctxT)
{
    const int tid = threadIdx.x;
    const int b  = blockIdx.x >> 2;
    const int hh = blockIdx.x & 3;
    const int d  = tid >> 3;
    const int e0 = (tid & 7) << 2;
    float sx = 0.f, sy = 0.f, sz = 0.f, sw = 0.f, z = 0.f;
    for (int ch = 0; ch < NCHUNK; ++ch) {
        const size_t base = (((size_t)b * NCHUNK + ch) * 4 + hh) * 32 + d;
        const float4 v = *(const float4*)(Spart + base * 32 + e0);
        sx += v.x; sy += v.y; sz += v.z; sw += v.w;
        z += Zpart[base];
    }
    const float inv = 1.0f / (z * 16384.0f);
    // ctxT[b][h][e][d] packed bf16 h/l
    const size_t tb = (((size_t)b * 4 + hh) * 32) * 32 + d;
    ctxT[tb + (size_t)(e0 + 0) * 32] = bpack(sx * inv);
    ctxT[tb + (size_t)(e0 + 1) * 32] = bpack(sy * inv);
    ctxT[tb + (size_t)(e0 + 2) * 32] = bpack(sz * inv);
    ctxT[tb + (size_t)(e0 + 3) * 32] = bpack(sw * inv);
}

// K2: q GEMM -> softmax -> out-einsum -> Wout GEMM -> LayerNorm, all fused.
__global__ __launch_bounds__(256, 2)
void la_k2(const float* __restrict__ x,
           const ushort* __restrict__ Wqh, const ushort* __restrict__ Wql,
           const ushort* __restrict__ Woh, const ushort* __restrict__ Wol,
           const float* __restrict__ bout, const float* __restrict__ g,
           const uint* __restrict__ ctxT, float* __restrict__ outg)
{
    __shared__ __align__(16) char smb[66560];

    const int tid = threadIdx.x;
    const int b = blockIdx.y, chunk = blockIdx.x;
    const int p0 = chunk * TP;
    const int w = tid >> 6, l = tid & 63;
    const int l15 = l & 15, lg = l >> 4;
    const int ch2 = w >> 1;        // col half
    const int rp  = w & 1;         // row-tile parity

    // ---- phase 1: stage x -> xTh/xTl ----
    {
        const float* xb = x + (size_t)b * 128 * 16384 + p0;
        const int j = tid & 15, gq = tid >> 4;
        const int pb = j * 4;
#pragma unroll
        for (int u = 0; u < 2; ++u) {
            const int cb = gq * 4 + u * 64;
            const float4 xv0 = *(const float4*)(xb + (size_t)(cb + 0) * 16384 + pb);
            const float4 xv1 = *(const float4*)(xb + (size_t)(cb + 1) * 16384 + pb);
            const float4 xv2 = *(const float4*)(xb + (size_t)(cb + 2) * 16384 + pb);
            const float4 xv3 = *(const float4*)(xb + (size_t)(cb + 3) * 16384 + pb);
            float rc[4][4];
            rc[0][0] = xv0.x; rc[0][1] = xv0.y; rc[0][2] = xv0.z; rc[0][3] = xv0.w;
            rc[1][0] = xv1.x; rc[1][1] = xv1.y; rc[1][2] = xv1.z; rc[1][3] = xv1.w;
            rc[2][0] = xv2.x; rc[2][1] = xv2.y; rc[2][2] = xv2.z; rc[2][3] = xv2.w;
            rc[3][0] = xv3.x; rc[3][1] = xv3.y; rc[3][2] = xv3.z; rc[3][3] = xv3.w;
#pragma unroll
            for (int pp = 0; pp < 4; ++pp) {
                const uint2 s0 = bsplit(rc[0][pp]);
                const uint2 s1 = bsplit(rc[1][pp]);
                const uint2 s2u = bsplit(rc[2][pp]);
                const uint2 s3 = bsplit(rc[3][pp]);
                const int p = pb + pp;
                const int byt = (p * 256 + cb * 2) ^ ((p & 7) << 4);
                *(uint2*)(&smb[byt])         = make_uint2(s0.x | (s1.x << 16), s2u.x | (s3.x << 16));
                *(uint2*)(&smb[16384 + byt]) = make_uint2(s0.y | (s1.y << 16), s2u.y | (s3.y << 16));
            }
        }
    }
    __syncthreads();

    // ---- phase 2: q GEMM (Wqkv rows 0..127): C[128 q-rows][64 p] ----
    f32x4 qacc[4][2];
#pragma unroll
    for (int j = 0; j < 4; ++j)
#pragma unroll
        for (int ct = 0; ct < 2; ++ct) qacc[j][ct] = (f32x4){0.f, 0.f, 0.f, 0.f};
#pragma unroll
    for (int ks = 0; ks < 4; ++ks) {
        short8 Bh[2], Bl[2];
#pragma unroll
        for (int ct = 0; ct < 2; ++ct) {
            const int p = ch2 * 32 + ct * 16 + l15;
            const int byt = (p * 256 + (ks * 32 + lg * 8) * 2) ^ ((p & 7) << 4);
            Bh[ct] = *(const short8*)(&smb[byt]);
            Bl[ct] = *(const short8*)(&smb[16384 + byt]);
        }
#pragma unroll
        for (int j = 0; j < 4; ++j) {
            const int T = rp + 2 * j;                  // row-tile 0..7
            const size_t aoff = (size_t)(T * 16 + l15) * 128 + ks * 32 + lg * 8;
            const short8 Ah_ = *(const short8*)(Wqh + aoff);
            const short8 Al_ = *(const short8*)(Wql + aoff);
#pragma unroll
            for (int ct = 0; ct < 2; ++ct) {
                qacc[j][ct] = MFMA(Ah_, Bh[ct], qacc[j][ct]);
                qacc[j][ct] = MFMA(Ah_, Bl[ct], qacc[j][ct]);
                qacc[j][ct] = MFMA(Al_, Bh[ct], qacc[j][ct]);
            }
        }
    }
    __syncthreads();   // xT reads done

    // ---- phase 3: write q fp32 to R0, [row][64p], p ^= ((row>>2)&1)<<4 ----
    {
        float* qsf = (float*)smb;
#pragma unroll
        for (int j = 0; j < 4; ++j) {
            const int T = rp + 2 * j;
#pragma unroll
            for (int ct = 0; ct < 2; ++ct) {
                const int p = ch2 * 32 + ct * 16 + l15;
#pragma unroll
                for (int i = 0; i < 4; ++i) {
                    const int row = T * 16 + lg * 4 + i;
                    qsf[row * 64 + (p ^ (((row >> 2) & 1) << 4))] = qacc[j][ct][i];
                }
            }
        }
    }
    __syncthreads();

    // ---- phase 4: softmax over d per (p, head), *scale; pack to qsT ----
    {
        const float* qsf = (const float*)smb;
        const int p  = tid & 63;
        const int sh = tid >> 6;
        float v[32];
        float m = -1e30f;
#pragma unroll
        for (int d = 0; d < 32; ++d) {
            const int row = sh * 32 + d;
            v[d] = qsf[row * 64 + (p ^ (((d >> 2) & 1) << 4))];
            m = fmaxf(m, v[d]);
        }
        float s = 0.f;
#pragma unroll
        for (int d = 0; d < 32; ++d) { v[d] = expf(v[d] - m); s += v[d]; }
        const float inv = 0.17677669529663687f / s;   // 32^-0.5 / s
        const int base = (sh * 64 + p) * 128;
        const int swz = ((p >> 2) & 7) << 4;
#pragma unroll
        for (int db = 0; db < 8; ++db) {
            uint4 pk;
            pk.x = bpack(v[db * 4 + 0] * inv);
            pk.y = bpack(v[db * 4 + 1] * inv);
            pk.z = bpack(v[db * 4 + 2] * inv);
            pk.w = bpack(v[db * 4 + 3] * inv);
            *(uint4*)(&smb[32768 + ((base + db * 16) ^ swz)]) = pk;
        }
    }
    __syncthreads();

    // ---- phase 5: out-einsum: out[e][p] = ctx^T q_s (K=32 per head) ----
    {
#pragma unroll
        for (int j = 0; j < 4; ++j) {
            const int rt = rp + 2 * j;
            const int sh = rt >> 1;          // head
            const int et = rt & 1;           // e-half within head
            const size_t aidx = ((((size_t)b * 4 + sh) * 32) + et * 16 + l15) * 32 + lg * 8;
            const uint4 a0 = *(const uint4*)(ctxT + aidx);
            const uint4 a1 = *(const uint4*)(ctxT + aidx + 4);
            const short8 Ah_ = lo8(a0, a1);
            const short8 Al_ = hi8(a0, a1);
            f32x4 oacc[2];
#pragma unroll
            for (int ct = 0; ct < 2; ++ct) {
                oacc[ct] = (f32x4){0.f, 0.f, 0.f, 0.f};
                const int p = ch2 * 32 + ct * 16 + l15;
                const int bb = (sh * 64 + p) * 128;
                const int swz = ((p >> 2) & 7) << 4;
                const uint4 r0 = *(const uint4*)(&smb[32768 + ((bb + lg * 32) ^ swz)]);
                const uint4 r1 = *(const uint4*)(&smb[32768 + ((bb + lg * 32 + 16) ^ swz)]);
                const short8 Bh_ = lo8(r0, r1);
                const short8 Bl_ = hi8(r0, r1);
                oacc[ct] = MFMA(Ah_, Bh_, oacc[ct]);
                oacc[ct] = MFMA(Ah_, Bl_, oacc[ct]);
                oacc[ct] = MFMA(Al_, Bh_, oacc[ct]);
            }
#pragma unroll
            for (int ct = 0; ct < 2; ++ct) {
                const int p = ch2 * 32 + ct * 16 + l15;
#pragma unroll
                for (int i = 0; i < 4; ++i) {
                    const int eg = rt * 16 + lg * 4 + i;
                    *(uint*)(&smb[(p * 512 + eg * 4) ^ ((p & 7) << 4)]) = bpack(oacc[ct][i]);
                }
            }
        }
    }
    __syncthreads();

    // ---- phase 6: y = Wout * out + bout ----
    f32x4 yacc[4][2];
#pragma unroll
    for (int j = 0; j < 4; ++j)
#pragma unroll
        for (int ct = 0; ct < 2; ++ct) yacc[j][ct] = (f32x4){0.f, 0.f, 0.f, 0.f};
#pragma unroll
    for (int ks = 0; ks < 4; ++ks) {
        short8 Bh[2], Bl[2];
#pragma unroll
        for (int ct = 0; ct < 2; ++ct) {
            const int p = ch2 * 32 + ct * 16 + l15;
            const int bb = p * 512 + (ks * 32 + lg * 8) * 4;
            const int swz = (p & 7) << 4;
            const uint4 r0 = *(const uint4*)(&smb[(bb) ^ swz]);
            const uint4 r1 = *(const uint4*)(&smb[(bb + 16) ^ swz]);
            Bh[ct] = lo8(r0, r1);
            Bl[ct] = hi8(r0, r1);
        }
#pragma unroll
        for (int j = 0; j < 4; ++j) {
            const int T = rp + 2 * j;
            const size_t aoff = (size_t)(T * 16 + l15) * 128 + ks * 32 + lg * 8;
            const short8 Ah_ = *(const short8*)(Woh + aoff);
            const short8 Al_ = *(const short8*)(Wol + aoff);
#pragma unroll
            for (int ct = 0; ct < 2; ++ct) {
                yacc[j][ct] = MFMA(Ah_, Bh[ct], yacc[j][ct]);
                yacc[j][ct] = MFMA(Ah_, Bl[ct], yacc[j][ct]);
                yacc[j][ct] = MFMA(Al_, Bh[ct], yacc[j][ct]);
            }
        }
    }

    // ---- phase 7: + bout, LayerNorm over 128 channels, * g, store ----
    float4 bo[4], gv[4];
#pragma unroll
    for (int j = 0; j < 4; ++j) {
        const int rbase = (rp + 2 * j) * 16 + lg * 4;
        bo[j] = *(const float4*)(bout + rbase);
        gv[j] = *(const float4*)(g + rbase);
    }
#pragma unroll
    for (int j = 0; j < 4; ++j)
#pragma unroll
        for (int ct = 0; ct < 2; ++ct) {
            yacc[j][ct][0] += bo[j].x;
            yacc[j][ct][1] += bo[j].y;
            yacc[j][ct][2] += bo[j].z;
            yacc[j][ct][3] += bo[j].w;
        }
    float* lnred = (float*)(smb + 65536);   // [64p][2rp][2]
    float sm[2], sq[2];
#pragma unroll
    for (int ct = 0; ct < 2; ++ct) {
        float s = 0.f, q = 0.f;
#pragma unroll
        for (int j = 0; j < 4; ++j)
#pragma unroll
            for (int i = 0; i < 4; ++i) {
                const float yv = yacc[j][ct][i];
                s += yv; q += yv * yv;
            }
        s += __shfl_xor(s, 16, 64); q += __shfl_xor(q, 16, 64);
        s += __shfl_xor(s, 32, 64); q += __shfl_xor(q, 32, 64);
        sm[ct] = s; sq[ct] = q;
    }
    if (lg == 0) {
#pragma unroll
        for (int ct = 0; ct < 2; ++ct) {
            const int p = ch2 * 32 + ct * 16 + l15;
            lnred[(p * 2 + rp) * 2 + 0] = sm[ct];
            lnred[(p * 2 + rp) * 2 + 1] = sq[ct];
        }
    }
    __syncthreads();
#pragma unroll
    for (int ct = 0; ct < 2; ++ct) {
        const int p = ch2 * 32 + ct * 16 + l15;
        const float st = lnred[(p * 2 + 0) * 2 + 0] + lnred[(p * 2 + 1) * 2 + 0];
        const float qt = lnred[(p * 2 + 0) * 2 + 1] + lnred[(p * 2 + 1) * 2 + 1];
        const float mean = st * (1.0f / 128.0f);
        const float var  = qt * (1.0f / 128.0f) - mean * mean;
        const float rstd = 1.0f / sqrtf(var + 1e-5f);
#pragma unroll
        for (int j = 0; j < 4; ++j) {
            const int rbase = (rp + 2 * j) * 16 + lg * 4;
            const float gg[4] = {gv[j].x, gv[j].y, gv[j].z, gv[j].w};
#pragma unroll
            for (int i = 0; i < 4; ++i) {
                const float val = (yacc[j][ct][i] - mean) * rstd * gg[i];
                outg[((size_t)b * 128 + rbase + i) * 16384 + p0 + p] = val;
            }
        }
    }
}

extern "C" void kernel_launch(void* const* d_in, const int* in_sizes, int n_in,
                              void* d_out, int out_size, void* d_ws, size_t ws_size,
                              hipStream_t stream) {
    const float* x    = (const float*)d_in[0];
    const float* Wqkv = (const float*)d_in[1];
    const float* Wout = (const float*)d_in[2];
    const float* bout = (const float*)d_in[3];
    const float* g    = (const float*)d_in[4];
    float* out = (float*)d_out;

    float* Spart = (float*)d_ws;                              // 32*64*4*32*32 floats
    float* Zpart = Spart + (size_t)32 * NCHUNK * 4 * 32 * 32; // 32*64*128 floats
    uint*  ctxT  = (uint*)(Zpart + (size_t)32 * NCHUNK * 4 * 32); // 32*4*32*32 u32
    ushort* Wqh  = (ushort*)(ctxT + (size_t)32 * 4 * 32 * 32);    // 384*128
    ushort* Wql  = Wqh + 384 * 128;
    ushort* Woh  = Wql + 384 * 128;                               // 128*128
    ushort* Wol  = Woh + 128 * 128;
    (void)in_sizes; (void)n_in; (void)out_size; (void)ws_size;

    wsplit<<<dim3(48), 256, 0, stream>>>(Wqkv, Wqh, Wql, 384 * 128);
    wsplit<<<dim3(16), 256, 0, stream>>>(Wout, Woh, Wol, 128 * 128);
    la_k1<<<dim3(NCHUNK, 32), 256, 0, stream>>>(x, Wqh, Wql, Spart, Zpart);
    la_k1_reduce<<<dim3(128), 256, 0, stream>>>(Spart, Zpart, ctxT);
    la_k2<<<dim3(256, 32), 256, 0, stream>>>(x, Wqh, Wql, Woh, Wol, bout, g, ctxT, out);
}

// Round 7
// 647.061 us; speedup vs baseline: 2.3057x; 1.0889x over previous
//
#include <hip/hip_runtime.h>
#include <math.h>

// LinearAttention: b=32, c=128, h=w=128 (n=16384), heads=4, dim_head=32.
// All GEMM-shaped work on split-bf16 MFMA (3-term: AhBh+AhBl+AlBh, fp32 acc).
//   wsplit: Wqkv and Wout -> bf16 hi/lo in ws.
//   K1:  W A-frags hoisted; k/v GEMM + S-accum on MFMA; Z in registers.
//   K1b: ctx reduce; emits ctxT[b][h][e][d] packed u32(bf16h | bf16l<<16).
//   K2:  q GEMM (wave w = head w) -> in-register softmax (shfl over lg)
//        -> qsT uint4 pack -> out-einsum MFMA -> Wout MFMA -> LN -> store.

#define TP 64
#define NCHUNK 64

typedef __attribute__((ext_vector_type(8))) short short8;
typedef __attribute__((ext_vector_type(4))) float f32x4;

__device__ __forceinline__ uint bf16r(float f) {
    uint u = __float_as_uint(f);
    return (u + 0x7FFFu + ((u >> 16) & 1u)) >> 16;   // RNE to bf16
}
__device__ __forceinline__ float bf16f(uint h) { return __uint_as_float(h << 16); }
__device__ __forceinline__ uint2 bsplit(float f) {
    uint h = bf16r(f);
    float r = f - bf16f(h);
    return make_uint2(h, bf16r(r));
}
__device__ __forceinline__ uint bpack(float f) {
    uint2 s = bsplit(f);
    return s.x | (s.y << 16);
}
__device__ __forceinline__ short8 lo8(uint4 a, uint4 b) {
    uint4 r;
    r.x = (a.x & 0xFFFFu) | (a.y << 16);
    r.y = (a.z & 0xFFFFu) | (a.w << 16);
    r.z = (b.x & 0xFFFFu) | (b.y << 16);
    r.w = (b.z & 0xFFFFu) | (b.w << 16);
    return __builtin_bit_cast(short8, r);
}
__device__ __forceinline__ short8 hi8(uint4 a, uint4 b) {
    uint4 r;
    r.x = (a.x >> 16) | (a.y & 0xFFFF0000u);
    r.y = (a.z >> 16) | (a.w & 0xFFFF0000u);
    r.z = (b.x >> 16) | (b.y & 0xFFFF0000u);
    r.w = (b.z >> 16) | (b.w & 0xFFFF0000u);
    return __builtin_bit_cast(short8, r);
}

// xT layout: byte = p*256 + 2c, XOR quad-swizzle with ((p ^ (p>>3)) & 7)<<4.
// Conflict-free for both stage stores and GEMM B-reads (verified in K1).
__device__ __forceinline__ int xswz(int p, int cbyte) {
    return (p * 256 + cbyte) ^ (((p ^ (p >> 3)) & 7) << 4);
}

__global__ __launch_bounds__(256)
void wsplit(const float* __restrict__ W, ushort* __restrict__ Wh,
            ushort* __restrict__ Wl, int n)
{
    const int base = (blockIdx.x * 256 + threadIdx.x) * 4;
    if (base + 3 < n) {
        const float4 f = *(const float4*)(W + base);
        const uint2 a = bsplit(f.x), b2 = bsplit(f.y), c = bsplit(f.z), d = bsplit(f.w);
        ushort4 hh; hh.x = (ushort)a.x; hh.y = (ushort)b2.x; hh.z = (ushort)c.x; hh.w = (ushort)d.x;
        ushort4 ll; ll.x = (ushort)a.y; ll.y = (ushort)b2.y; ll.z = (ushort)c.y; ll.w = (ushort)d.y;
        *(ushort4*)(Wh + base) = hh;
        *(ushort4*)(Wl + base) = ll;
    }
}

#define MFMA(A, B, C) __builtin_amdgcn_mfma_f32_16x16x32_bf16((A), (B), (C), 0, 0, 0)

__global__ __launch_bounds__(256, 2)
void la_k1(const float* __restrict__ x,
           const ushort* __restrict__ Wh, const ushort* __restrict__ Wl,
           float* __restrict__ Spart, float* __restrict__ Zpart)
{
    // bytes [0,16384):      xTh bf16 [64p][128c], xswz
    // bytes [16384,32768):  xTl
    // bytes [0,32768):      ekp u32 [128r][64p], byte = (r*256 + 4p) ^ ((r&7)<<4)
    // bytes [32768,65536):  vbp u32 [128r][64p]
    __shared__ __align__(16) char smb[65536];

    const int tid = threadIdx.x;
    const int b = blockIdx.y, chunk = blockIdx.x;
    const int w = tid >> 6, l = tid & 63;
    const int l15 = l & 15, lg = l >> 4;

    // ---- prologue: hoist A-fragments. wave w owns row-tiles T = rt*4 + w ----
    short8 Ah[4][4], Al[4][4];
#pragma unroll
    for (int rt = 0; rt < 4; ++rt) {
        const int T = rt * 4 + w;
#pragma unroll
        for (int ks = 0; ks < 4; ++ks) {
            const size_t aoff = (size_t)(128 + T * 16 + l15) * 128 + ks * 32 + lg * 8;
            Ah[rt][ks] = *(const short8*)(Wh + aoff);
            Al[rt][ks] = *(const short8*)(Wl + aoff);
        }
    }

    f32x4 s2[2][2];            // S accumulator, head = w
#pragma unroll
    for (int i = 0; i < 2; ++i)
#pragma unroll
        for (int j = 0; j < 2; ++j) s2[i][j] = (f32x4){0.f, 0.f, 0.f, 0.f};
    float zrow[2][4];          // Z partials for k-tiles rt=0,1
#pragma unroll
    for (int i = 0; i < 2; ++i)
#pragma unroll
        for (int j = 0; j < 4; ++j) zrow[i][j] = 0.f;

    for (int t = 0; t < 4; ++t) {
        const int p0 = (chunk * 4 + t) * TP;
        const float* xb = x + (size_t)b * 128 * 16384 + p0;

        // ---- stage x -> xTh/xTl (in-register 4x4 transpose) ----
        {
            const int j = tid & 15, g = tid >> 4;
            const int pb = j * 4;
#pragma unroll
            for (int u = 0; u < 2; ++u) {
                const int cb = g * 4 + u * 64;
                const float4 xv0 = *(const float4*)(xb + (size_t)(cb + 0) * 16384 + pb);
                const float4 xv1 = *(const float4*)(xb + (size_t)(cb + 1) * 16384 + pb);
                const float4 xv2 = *(const float4*)(xb + (size_t)(cb + 2) * 16384 + pb);
                const float4 xv3 = *(const float4*)(xb + (size_t)(cb + 3) * 16384 + pb);
                float rc[4][4];
                rc[0][0] = xv0.x; rc[0][1] = xv0.y; rc[0][2] = xv0.z; rc[0][3] = xv0.w;
                rc[1][0] = xv1.x; rc[1][1] = xv1.y; rc[1][2] = xv1.z; rc[1][3] = xv1.w;
                rc[2][0] = xv2.x; rc[2][1] = xv2.y; rc[2][2] = xv2.z; rc[2][3] = xv2.w;
                rc[3][0] = xv3.x; rc[3][1] = xv3.y; rc[3][2] = xv3.z; rc[3][3] = xv3.w;
#pragma unroll
                for (int pp = 0; pp < 4; ++pp) {
                    const uint2 s0 = bsplit(rc[0][pp]);
                    const uint2 s1 = bsplit(rc[1][pp]);
                    const uint2 s2u = bsplit(rc[2][pp]);
                    const uint2 s3 = bsplit(rc[3][pp]);
                    const int p = pb + pp;
                    const int byt = xswz(p, cb * 2);
                    *(uint2*)(&smb[byt])         = make_uint2(s0.x | (s1.x << 16), s2u.x | (s3.x << 16));
                    *(uint2*)(&smb[16384 + byt]) = make_uint2(s0.y | (s1.y << 16), s2u.y | (s3.y << 16));
                }
            }
        }
        __syncthreads();

        // ---- k/v GEMM: registers-A x LDS-B, pure MFMA ----
        f32x4 acc[4][4];
#pragma unroll
        for (int rt = 0; rt < 4; ++rt)
#pragma unroll
            for (int ct = 0; ct < 4; ++ct) acc[rt][ct] = (f32x4){0.f, 0.f, 0.f, 0.f};
#pragma unroll
        for (int ks = 0; ks < 4; ++ks) {
#pragma unroll
            for (int ct = 0; ct < 4; ++ct) {
                const int p = ct * 16 + l15;
                const int byt = xswz(p, (ks * 32 + lg * 8) * 2);
                const short8 Bh_ = *(const short8*)(&smb[byt]);
                const short8 Bl_ = *(const short8*)(&smb[16384 + byt]);
#pragma unroll
                for (int rt = 0; rt < 4; ++rt) {
                    acc[rt][ct] = MFMA(Ah[rt][ks], Bh_, acc[rt][ct]);
                    acc[rt][ct] = MFMA(Ah[rt][ks], Bl_, acc[rt][ct]);
                    acc[rt][ct] = MFMA(Al[rt][ks], Bh_, acc[rt][ct]);
                }
            }
        }
        __syncthreads();   // all xT reads done; ek may overwrite

        // ---- producer: exp(k)/v -> packed u32 rows; Z in registers ----
#pragma unroll
        for (int rt = 0; rt < 4; ++rt) {
            const int T = rt * 4 + w;
            const int rbase = (T & 7) * 16 + lg * 4;
#pragma unroll
            for (int ct = 0; ct < 4; ++ct) {
                const int p = ct * 16 + l15;
#pragma unroll
                for (int i = 0; i < 4; ++i) {
                    float val = acc[rt][ct][i];
                    if (rt < 2) {                       // k tile
                        val = expf(val);
                        zrow[rt & 1][i] += val;
                    }
                    const int r = rbase + i;
                    const uint2 hl = bsplit(val);
                    const int byt = (r * 256 + p * 4) ^ ((r & 7) << 4);
                    *(uint*)(&smb[(rt < 2 ? 0 : 32768) + byt]) = hl.x | (hl.y << 16);
                }
            }
        }
        __syncthreads();

        // ---- S-phase MFMA: head w, S[32d][32e] += ek * v^T over 64 p ----
#pragma unroll
        for (int ks2 = 0; ks2 < 2; ++ks2) {
            const int pq = ks2 * 32 + lg * 8;
            short8 A2h[2], A2l[2], B2h[2], B2l[2];
#pragma unroll
            for (int rt2 = 0; rt2 < 2; ++rt2) {
                const int r = w * 32 + rt2 * 16 + l15;
                const int b0 = (r * 256 + pq * 4) ^ ((r & 7) << 4);
                const int b1 = (r * 256 + pq * 4 + 16) ^ ((r & 7) << 4);
                const uint4 q0 = *(const uint4*)(&smb[b0]);
                const uint4 q1 = *(const uint4*)(&smb[b1]);
                A2h[rt2] = lo8(q0, q1);
                A2l[rt2] = hi8(q0, q1);
                const uint4 r0 = *(const uint4*)(&smb[32768 + b0]);
                const uint4 r1 = *(const uint4*)(&smb[32768 + b1]);
                B2h[rt2] = lo8(r0, r1);
                B2l[rt2] = hi8(r0, r1);
            }
#pragma unroll
            for (int rt2 = 0; rt2 < 2; ++rt2)
#pragma unroll
                for (int ct2 = 0; ct2 < 2; ++ct2) {
                    s2[rt2][ct2] = MFMA(A2h[rt2], B2h[ct2], s2[rt2][ct2]);
                    s2[rt2][ct2] = MFMA(A2h[rt2], B2l[ct2], s2[rt2][ct2]);
                    s2[rt2][ct2] = MFMA(A2l[rt2], B2h[ct2], s2[rt2][ct2]);
                }
        }
        __syncthreads();   // ek/vb consumed; next tile may restage
    }

    // ---- write S partials: Spart[b][ch][head=w][d][e] ----
    const size_t sbase = (((size_t)b * NCHUNK + chunk) * 4 + w) * 1024;
#pragma unroll
    for (int rt2 = 0; rt2 < 2; ++rt2)
#pragma unroll
        for (int ct2 = 0; ct2 < 2; ++ct2)
#pragma unroll
            for (int i = 0; i < 4; ++i) {
                const int d = rt2 * 16 + lg * 4 + i;
                const int e = ct2 * 16 + l15;
                Spart[sbase + d * 32 + e] = s2[rt2][ct2][i];
            }

    // ---- Z: butterfly-reduce over l15, write per k-row ----
#pragma unroll
    for (int rt = 0; rt < 2; ++rt)
#pragma unroll
        for (int i = 0; i < 4; ++i) {
            float z = zrow[rt][i];
            z += __shfl_xor(z, 1, 64);
            z += __shfl_xor(z, 2, 64);
            z += __shfl_xor(z, 4, 64);
            z += __shfl_xor(z, 8, 64);
            if (l15 == 0) {
                const int T = rt * 4 + w;   // k tile index 0..7
                Zpart[((size_t)b * NCHUNK + chunk) * 128 + T * 16 + lg * 4 + i] = z;
            }
        }
}

__global__ __launch_bounds__(256, 1)
void la_k1_reduce(const float* __restrict__ Spart, const float* __restrict__ Zpart,
                  uint* __restrict__ ctxT)
{
    const int tid = threadIdx.x;
    const int b  = blockIdx.x >> 2;
    const int hh = blockIdx.x & 3;
    const int d  = tid >> 3;
    const int e0 = (tid & 7) << 2;
    float sx = 0.f, sy = 0.f, sz = 0.f, sw = 0.f, z = 0.f;
    for (int ch = 0; ch < NCHUNK; ++ch) {
        const size_t base = (((size_t)b * NCHUNK + ch) * 4 + hh) * 32 + d;
        const float4 v = *(const float4*)(Spart + base * 32 + e0);
        sx += v.x; sy += v.y; sz += v.z; sw += v.w;
        z += Zpart[base];
    }
    const float inv = 1.0f / (z * 16384.0f);
    // ctxT[b][h][e][d] packed bf16 h/l
    const size_t tb = (((size_t)b * 4 + hh) * 32) * 32 + d;
    ctxT[tb + (size_t)(e0 + 0) * 32] = bpack(sx * inv);
    ctxT[tb + (size_t)(e0 + 1) * 32] = bpack(sy * inv);
    ctxT[tb + (size_t)(e0 + 2) * 32] = bpack(sz * inv);
    ctxT[tb + (size_t)(e0 + 3) * 32] = bpack(sw * inv);
}

// K2: q GEMM (wave w = head w) -> in-register softmax -> qsT pack ->
//     out-einsum -> Wout GEMM -> LayerNorm, all fused.
// LDS regions:
//   R0 [0,32768):      xTh/xTl (xswz)  ->  out u32 [64p][128e], byte=(p*512+e*4)^((p&7)<<4)
//   R1 [32768,65536):  qsT u32 [4sh][64p][32d], byte=((sh*64+p)*128+d*4)^((p&7)<<4)
//   R2 [65536,66560):  lnred [64p][2rp][2]
__global__ __launch_bounds__(256, 2)
void la_k2(const float* __restrict__ x,
           const ushort* __restrict__ Wqh, const ushort* __restrict__ Wql,
           const ushort* __restrict__ Woh, const ushort* __restrict__ Wol,
           const float* __restrict__ bout, const float* __restrict__ g,
           const uint* __restrict__ ctxT, float* __restrict__ outg)
{
    __shared__ __align__(16) char smb[66560];

    const int tid = threadIdx.x;
    const int b = blockIdx.y, chunk = blockIdx.x;
    const int p0 = chunk * TP;
    const int w = tid >> 6, l = tid & 63;
    const int l15 = l & 15, lg = l >> 4;
    const int ch2 = w >> 1;        // col half (phases 5-7)
    const int rp  = w & 1;         // row-tile parity (phases 5-7)

    // ---- prologue: hoist Wq A-frags for head w (q rows 32w..32w+31) ----
    short8 AqH[2][4], AqL[2][4];
#pragma unroll
    for (int t_ = 0; t_ < 2; ++t_)
#pragma unroll
        for (int ks = 0; ks < 4; ++ks) {
            const size_t aoff = (size_t)((2 * w + t_) * 16 + l15) * 128 + ks * 32 + lg * 8;
            AqH[t_][ks] = *(const short8*)(Wqh + aoff);
            AqL[t_][ks] = *(const short8*)(Wql + aoff);
        }

    // ---- phase 1: stage x -> xTh/xTl (xswz, conflict-free) ----
    {
        const float* xb = x + (size_t)b * 128 * 16384 + p0;
        const int j = tid & 15, gq = tid >> 4;
        const int pb = j * 4;
#pragma unroll
        for (int u = 0; u < 2; ++u) {
            const int cb = gq * 4 + u * 64;
            const float4 xv0 = *(const float4*)(xb + (size_t)(cb + 0) * 16384 + pb);
            const float4 xv1 = *(const float4*)(xb + (size_t)(cb + 1) * 16384 + pb);
            const float4 xv2 = *(const float4*)(xb + (size_t)(cb + 2) * 16384 + pb);
            const float4 xv3 = *(const float4*)(xb + (size_t)(cb + 3) * 16384 + pb);
            float rc[4][4];
            rc[0][0] = xv0.x; rc[0][1] = xv0.y; rc[0][2] = xv0.z; rc[0][3] = xv0.w;
            rc[1][0] = xv1.x; rc[1][1] = xv1.y; rc[1][2] = xv1.z; rc[1][3] = xv1.w;
            rc[2][0] = xv2.x; rc[2][1] = xv2.y; rc[2][2] = xv2.z; rc[2][3] = xv2.w;
            rc[3][0] = xv3.x; rc[3][1] = xv3.y; rc[3][2] = xv3.z; rc[3][3] = xv3.w;
#pragma unroll
            for (int pp = 0; pp < 4; ++pp) {
                const uint2 s0 = bsplit(rc[0][pp]);
                const uint2 s1 = bsplit(rc[1][pp]);
                const uint2 s2u = bsplit(rc[2][pp]);
                const uint2 s3 = bsplit(rc[3][pp]);
                const int p = pb + pp;
                const int byt = xswz(p, cb * 2);
                *(uint2*)(&smb[byt])         = make_uint2(s0.x | (s1.x << 16), s2u.x | (s3.x << 16));
                *(uint2*)(&smb[16384 + byt]) = make_uint2(s0.y | (s1.y << 16), s2u.y | (s3.y << 16));
            }
        }
    }
    __syncthreads();

    // ---- phase 2: q GEMM: wave w computes rows 32w..32w+31 x all 64 p ----
    f32x4 qacc[2][4];
#pragma unroll
    for (int t_ = 0; t_ < 2; ++t_)
#pragma unroll
        for (int ct = 0; ct < 4; ++ct) qacc[t_][ct] = (f32x4){0.f, 0.f, 0.f, 0.f};
#pragma unroll
    for (int ks = 0; ks < 4; ++ks) {
#pragma unroll
        for (int ct = 0; ct < 4; ++ct) {
            const int p = ct * 16 + l15;
            const int byt = xswz(p, (ks * 32 + lg * 8) * 2);
            const short8 Bh_ = *(const short8*)(&smb[byt]);
            const short8 Bl_ = *(const short8*)(&smb[16384 + byt]);
#pragma unroll
            for (int t_ = 0; t_ < 2; ++t_) {
                qacc[t_][ct] = MFMA(AqH[t_][ks], Bh_, qacc[t_][ct]);
                qacc[t_][ct] = MFMA(AqH[t_][ks], Bl_, qacc[t_][ct]);
                qacc[t_][ct] = MFMA(AqL[t_][ks], Bh_, qacc[t_][ct]);
            }
        }
    }

    // ---- phase 3: in-register softmax over d (4 lanes via shfl), pack qsT ----
    {
#pragma unroll
        for (int ct = 0; ct < 4; ++ct) {
            const int p = ct * 16 + l15;
            float vv[2][4];
            float m = -1e30f;
#pragma unroll
            for (int t_ = 0; t_ < 2; ++t_)
#pragma unroll
                for (int i = 0; i < 4; ++i) {
                    vv[t_][i] = qacc[t_][ct][i];
                    m = fmaxf(m, vv[t_][i]);
                }
            m = fmaxf(m, __shfl_xor(m, 16, 64));
            m = fmaxf(m, __shfl_xor(m, 32, 64));
            float s = 0.f;
#pragma unroll
            for (int t_ = 0; t_ < 2; ++t_)
#pragma unroll
                for (int i = 0; i < 4; ++i) {
                    vv[t_][i] = expf(vv[t_][i] - m);
                    s += vv[t_][i];
                }
            s += __shfl_xor(s, 16, 64);
            s += __shfl_xor(s, 32, 64);
            const float inv = 0.17677669529663687f / s;   // 32^-0.5 / s
            const int basep = (w * 64 + p) * 128;
            const int swzq = (p & 7) << 4;
#pragma unroll
            for (int t_ = 0; t_ < 2; ++t_) {
                uint4 pk;
                pk.x = bpack(vv[t_][0] * inv);
                pk.y = bpack(vv[t_][1] * inv);
                pk.z = bpack(vv[t_][2] * inv);
                pk.w = bpack(vv[t_][3] * inv);
                *(uint4*)(&smb[32768 + ((basep + (t_ * 16 + lg * 4) * 4) ^ swzq)]) = pk;
            }
        }
    }
    __syncthreads();   // qsT ready; all xT reads done (R0 reusable)

    // ---- phase 5: out-einsum: out[e][p] = ctx^T q_s (K=32 per head) ----
    {
#pragma unroll
        for (int j = 0; j < 4; ++j) {
            const int rt = rp + 2 * j;
            const int sh = rt >> 1;          // head
            const int et = rt & 1;           // e-half within head
            const size_t aidx = ((((size_t)b * 4 + sh) * 32) + et * 16 + l15) * 32 + lg * 8;
            const uint4 a0 = *(const uint4*)(ctxT + aidx);
            const uint4 a1 = *(const uint4*)(ctxT + aidx + 4);
            const short8 Ah_ = lo8(a0, a1);
            const short8 Al_ = hi8(a0, a1);
            f32x4 oacc[2];
#pragma unroll
            for (int ct = 0; ct < 2; ++ct) {
                oacc[ct] = (f32x4){0.f, 0.f, 0.f, 0.f};
                const int p = ch2 * 32 + ct * 16 + l15;
                const int bbq = (sh * 64 + p) * 128;
                const int swzq = (p & 7) << 4;
                const uint4 r0 = *(const uint4*)(&smb[32768 + ((bbq + lg * 32) ^ swzq)]);
                const uint4 r1 = *(const uint4*)(&smb[32768 + ((bbq + lg * 32 + 16) ^ swzq)]);
                const short8 Bh_ = lo8(r0, r1);
                const short8 Bl_ = hi8(r0, r1);
                oacc[ct] = MFMA(Ah_, Bh_, oacc[ct]);
                oacc[ct] = MFMA(Ah_, Bl_, oacc[ct]);
                oacc[ct] = MFMA(Al_, Bh_, oacc[ct]);
            }
            // write out-tile as uint4 (4 consecutive e), conflict-free
#pragma unroll
            for (int ct = 0; ct < 2; ++ct) {
                const int p = ch2 * 32 + ct * 16 + l15;
                const int e0 = rt * 16 + lg * 4;
                uint4 pk;
                pk.x = bpack(oacc[ct][0]);
                pk.y = bpack(oacc[ct][1]);
                pk.z = bpack(oacc[ct][2]);
                pk.w = bpack(oacc[ct][3]);
                *(uint4*)(&smb[(p * 512 + e0 * 4) ^ ((p & 7) << 4)]) = pk;
            }
        }
    }
    __syncthreads();

    // ---- phase 6: y = Wout * out + bout ----
    f32x4 yacc[4][2];
#pragma unroll
    for (int j = 0; j < 4; ++j)
#pragma unroll
        for (int ct = 0; ct < 2; ++ct) yacc[j][ct] = (f32x4){0.f, 0.f, 0.f, 0.f};
#pragma unroll
    for (int ks = 0; ks < 4; ++ks) {
        short8 Bh[2], Bl[2];
#pragma unroll
        for (int ct = 0; ct < 2; ++ct) {
            const int p = ch2 * 32 + ct * 16 + l15;
            const int bb = p * 512 + (ks * 32 + lg * 8) * 4;
            const int swz = (p & 7) << 4;
            const uint4 r0 = *(const uint4*)(&smb[(bb) ^ swz]);
            const uint4 r1 = *(const uint4*)(&smb[(bb + 16) ^ swz]);
            Bh[ct] = lo8(r0, r1);
            Bl[ct] = hi8(r0, r1);
        }
#pragma unroll
        for (int j = 0; j < 4; ++j) {
            const int T = rp + 2 * j;
            const size_t aoff = (size_t)(T * 16 + l15) * 128 + ks * 32 + lg * 8;
            const short8 Ah_ = *(const short8*)(Woh + aoff);
            const short8 Al_ = *(const short8*)(Wol + aoff);
#pragma unroll
            for (int ct = 0; ct < 2; ++ct) {
                yacc[j][ct] = MFMA(Ah_, Bh[ct], yacc[j][ct]);
                yacc[j][ct] = MFMA(Ah_, Bl[ct], yacc[j][ct]);
                yacc[j][ct] = MFMA(Al_, Bh[ct], yacc[j][ct]);
            }
        }
    }

    // ---- phase 7: + bout, LayerNorm over 128 channels, * g, store ----
    float4 bo[4], gv[4];
#pragma unroll
    for (int j = 0; j < 4; ++j) {
        const int rbase = (rp + 2 * j) * 16 + lg * 4;
        bo[j] = *(const float4*)(bout + rbase);
        gv[j] = *(const float4*)(g + rbase);
    }
#pragma unroll
    for (int j = 0; j < 4; ++j)
#pragma unroll
        for (int ct = 0; ct < 2; ++ct) {
            yacc[j][ct][0] += bo[j].x;
            yacc[j][ct][1] += bo[j].y;
            yacc[j][ct][2] += bo[j].z;
            yacc[j][ct][3] += bo[j].w;
        }
    float* lnred = (float*)(smb + 65536);   // [64p][2rp][2]
    float sm[2], sq[2];
#pragma unroll
    for (int ct = 0; ct < 2; ++ct) {
        float s = 0.f, q = 0.f;
#pragma unroll
        for (int j = 0; j < 4; ++j)
#pragma unroll
            for (int i = 0; i < 4; ++i) {
                const float yv = yacc[j][ct][i];
                s += yv; q += yv * yv;
            }
        s += __shfl_xor(s, 16, 64); q += __shfl_xor(q, 16, 64);
        s += __shfl_xor(s, 32, 64); q += __shfl_xor(q, 32, 64);
        sm[ct] = s; sq[ct] = q;
    }
    if (lg == 0) {
#pragma unroll
        for (int ct = 0; ct < 2; ++ct) {
            const int p = ch2 * 32 + ct * 16 + l15;
            lnred[(p * 2 + rp) * 2 + 0] = sm[ct];
            lnred[(p * 2 + rp) * 2 + 1] = sq[ct];
        }
    }
    __syncthreads();
#pragma unroll
    for (int ct = 0; ct < 2; ++ct) {
        const int p = ch2 * 32 + ct * 16 + l15;
        const float st = lnred[(p * 2 + 0) * 2 + 0] + lnred[(p * 2 + 1) * 2 + 0];
        const float qt = lnred[(p * 2 + 0) * 2 + 1] + lnred[(p * 2 + 1) * 2 + 1];
        const float mean = st * (1.0f / 128.0f);
        const float var  = qt * (1.0f / 128.0f) - mean * mean;
        const float rstd = 1.0f / sqrtf(var + 1e-5f);
#pragma unroll
        for (int j = 0; j < 4; ++j) {
            const int rbase = (rp + 2 * j) * 16 + lg * 4;
            const float gg[4] = {gv[j].x, gv[j].y, gv[j].z, gv[j].w};
#pragma unroll
            for (int i = 0; i < 4; ++i) {
                const float val = (yacc[j][ct][i] - mean) * rstd * gg[i];
                outg[((size_t)b * 128 + rbase + i) * 16384 + p0 + p] = val;
            }
        }
    }
}

extern "C" void kernel_launch(void* const* d_in, const int* in_sizes, int n_in,
                              void* d_out, int out_size, void* d_ws, size_t ws_size,
                              hipStream_t stream) {
    const float* x    = (const float*)d_in[0];
    const float* Wqkv = (const float*)d_in[1];
    const float* Wout = (const float*)d_in[2];
    const float* bout = (const float*)d_in[3];
    const float* g    = (const float*)d_in[4];
    float* out = (float*)d_out;

    float* Spart = (float*)d_ws;                              // 32*64*4*32*32 floats
    float* Zpart = Spart + (size_t)32 * NCHUNK * 4 * 32 * 32; // 32*64*128 floats
    uint*  ctxT  = (uint*)(Zpart + (size_t)32 * NCHUNK * 4 * 32); // 32*4*32*32 u32
    ushort* Wqh  = (ushort*)(ctxT + (size_t)32 * 4 * 32 * 32);    // 384*128
    ushort* Wql  = Wqh + 384 * 128;
    ushort* Woh  = Wql + 384 * 128;                               // 128*128
    ushort* Wol  = Woh + 128 * 128;
    (void)in_sizes; (void)n_in; (void)out_size; (void)ws_size;

    wsplit<<<dim3(48), 256, 0, stream>>>(Wqkv, Wqh, Wql, 384 * 128);
    wsplit<<<dim3(16), 256, 0, stream>>>(Wout, Woh, Wol, 128 * 128);
    la_k1<<<dim3(NCHUNK, 32), 256, 0, stream>>>(x, Wqh, Wql, Spart, Zpart);
    la_k1_reduce<<<dim3(128), 256, 0, stream>>>(Spart, Zpart, ctxT);
    la_k2<<<dim3(256, 32), 256, 0, stream>>>(x, Wqh, Wql, Woh, Wol, bout, g, ctxT, out);
}